// Round 4
// baseline (184.713 us; speedup 1.0000x reference)
//
#include <hip/hip_runtime.h>
#include <hip/hip_bf16.h>

// N=4, S=2048, D_MODEL=1024, HEADS=16, HEAD_DIM=64. M = 8192 tokens, E = 3072.

typedef __hip_bfloat16 bf16;
using bf16x8 = __attribute__((ext_vector_type(8))) short;
using f32x4  = __attribute__((ext_vector_type(4))) float;

__device__ __forceinline__ float b2f(unsigned short u) {
    return __uint_as_float(((unsigned)u) << 16);
}
__device__ __forceinline__ unsigned short f2b(float f) {
    bf16 h = __float2bfloat16(f);
    return *reinterpret_cast<unsigned short*>(&h);
}
__device__ __forceinline__ void store1(float* p, float v) { *p = v; }
__device__ __forceinline__ void store1(bf16* p, float v) { *p = __float2bfloat16(v); }

// async global->LDS, 16B per lane. LDS dest = wave-uniform base + lane*16.
__device__ __forceinline__ void gload_lds16(const bf16* g, bf16* l) {
    __builtin_amdgcn_global_load_lds(
        (const __attribute__((address_space(1))) void*)g,
        (__attribute__((address_space(3))) void*)l, 16, 0, 0);
}

#define BAR() __builtin_amdgcn_s_barrier()
#define LGK0()                                                  \
    do {                                                        \
        asm volatile("s_waitcnt lgkmcnt(0)" ::: "memory");      \
        __builtin_amdgcn_sched_barrier(0);                      \
    } while (0)
#define VMC(N) asm volatile("s_waitcnt vmcnt(" #N ")" ::: "memory")

// ============================================================================
// 8-phase 256x256 GEMM (T2 swizzle + T3/T4 counted-vmcnt phases + T5 setprio)
// C[M][N] = A[M][K] * B[N][K]^T + bias[N].  K multiple of 128.
// 512 thr = 8 waves (2Mx4N), per-wave out 128x64 = acc[8][4] f32x4.
// LDS 128KB: smem[buf][A/B][256*64] bf16, st_16x32 swizzle (read side),
// staged linear via global_load_lds with inverse-swizzled GLOBAL source.
// Stage rotation (derived, regions read-dead, 3-phase landing margin):
//   ph1: T1.A1 | ph3: NT0.B0,B1 | ph4: NT0.A0 +vmcnt(6) | ph5: NT0.A1
//   ph6: -     | ph7: NT1.B0,B1 | ph8: NT1.A0 +vmcnt(6)
// Reads: phX.1: A(kk0)x8 + B(kk0)x4; phX.2: B(kk1)x4; phX.3: A(kk1)x8.
// MFMA: phX.1: kk0*n01; phX.2: kk0*n23; phX.3: kk1*n01; phX.4: kk1*n23.
// ============================================================================
template <typename CT>
__global__ __launch_bounds__(512, 2)
void gemm8p(const bf16* __restrict__ A, const bf16* __restrict__ B,
            const float* __restrict__ bias, CT* __restrict__ C,
            int M, int N, int K) {
    __shared__ alignas(1024) bf16 smem[2][2][16384];  // [buf][A/B][256*64]

    const int t    = threadIdx.x;
    const int lane = t & 63;
    const int wid  = t >> 6;
    const int wr   = wid >> 2;   // 0..1  (M half)
    const int wc   = wid & 3;    // 0..3  (N quarter)
    const int m0   = blockIdx.y * 256;
    const int n0   = blockIdx.x * 256;
    const int nt   = K / 64;
    const int iters = nt / 2;

    // staging source coords (inverse st_16x32 swizzle on global k-offset)
    const int srow = wid * 8 + (lane >> 3);                     // 0..63
    const int kel  = ((lane & 7) * 8) ^ ((lane & 32) ? 16 : 0); // 0..120

    auto stageA = [&](int tt, int h) {
        if (tt >= nt) return;
        bf16* lp = &smem[tt & 1][0][h * 8192 + wid * 512];
        const bf16* gp = A + (size_t)(m0 + h * 128 + srow) * K + tt * 64 + kel;
#pragma unroll
        for (int i = 0; i < 2; ++i)
            gload_lds16(gp + (size_t)i * 64 * K, lp + i * 4096);
    };
    auto stageB = [&](int tt, int h) {
        if (tt >= nt) return;
        bf16* lp = &smem[tt & 1][1][h * 8192 + wid * 512];
        const bf16* gp = B + (size_t)(n0 + h * 128 + srow) * K + tt * 64 + kel;
#pragma unroll
        for (int i = 0; i < 2; ++i)
            gload_lds16(gp + (size_t)i * 64 * K, lp + i * 4096);
    };

    // swizzled ds_read of one 16x16x32 fragment
    const int arow_base = wr * 128 + (lane & 15);
    const int brow_base = wc * 64 + (lane & 15);
    const int kqb       = (lane >> 4) * 16;  // k byte sub-offset
    auto LDA = [&](int buf, int kk, int m) -> bf16x8 {
        int ab = (arow_base + m * 16) * 128 + kk * 64 + kqb;
        ab ^= ((ab >> 9) & 1) << 5;
        return *(const bf16x8*)((const char*)&smem[buf][0][0] + ab);
    };
    auto LDB = [&](int buf, int kk, int n) -> bf16x8 {
        int bb = (brow_base + n * 16) * 128 + kk * 64 + kqb;
        bb ^= ((bb >> 9) & 1) << 5;
        return *(const bf16x8*)((const char*)&smem[buf][1][0] + bb);
    };

    f32x4 acc[8][4] = {};
    bf16x8 af[8], bk0[4], bk1[4];

    // prologue: t0 full, t1 all but A1; wait t0 landed (3 halves in flight)
    stageB(0, 0); stageB(0, 1); stageA(0, 0); stageA(0, 1);
    stageB(1, 0); stageB(1, 1); stageA(1, 0);
    VMC(6);
    BAR();

    for (int it = 0; it < iters; ++it) {
        const int t1 = 2 * it + 1, q0t = 2 * it + 2, q1t = 2 * it + 3;
        const bool last = (it == iters - 1);

        // ---------------- tile T0 (buf 0) ----------------
        // ph1
#pragma unroll
        for (int m = 0; m < 8; ++m) af[m] = LDA(0, 0, m);
#pragma unroll
        for (int n = 0; n < 4; ++n) bk0[n] = LDB(0, 0, n);
        stageA(t1, 1);
        BAR(); LGK0();
        __builtin_amdgcn_s_setprio(1);
#pragma unroll
        for (int m = 0; m < 8; ++m) {
            acc[m][0] = __builtin_amdgcn_mfma_f32_16x16x32_bf16(af[m], bk0[0], acc[m][0], 0, 0, 0);
            acc[m][1] = __builtin_amdgcn_mfma_f32_16x16x32_bf16(af[m], bk0[1], acc[m][1], 0, 0, 0);
        }
        __builtin_amdgcn_s_setprio(0);
        BAR();
        // ph2
#pragma unroll
        for (int n = 0; n < 4; ++n) bk1[n] = LDB(0, 1, n);
        stageB(q0t, 0); stageB(q0t, 1);
        BAR(); LGK0();
        __builtin_amdgcn_s_setprio(1);
#pragma unroll
        for (int m = 0; m < 8; ++m) {
            acc[m][2] = __builtin_amdgcn_mfma_f32_16x16x32_bf16(af[m], bk0[2], acc[m][2], 0, 0, 0);
            acc[m][3] = __builtin_amdgcn_mfma_f32_16x16x32_bf16(af[m], bk0[3], acc[m][3], 0, 0, 0);
        }
        __builtin_amdgcn_s_setprio(0);
        BAR();
        // ph3
#pragma unroll
        for (int m = 0; m < 8; ++m) af[m] = LDA(0, 1, m);
        stageA(q0t, 0);
        BAR(); LGK0();
        __builtin_amdgcn_s_setprio(1);
#pragma unroll
        for (int m = 0; m < 8; ++m) {
            acc[m][0] = __builtin_amdgcn_mfma_f32_16x16x32_bf16(af[m], bk1[0], acc[m][0], 0, 0, 0);
            acc[m][1] = __builtin_amdgcn_mfma_f32_16x16x32_bf16(af[m], bk1[1], acc[m][1], 0, 0, 0);
        }
        __builtin_amdgcn_s_setprio(0);
        BAR();
        // ph4
        stageA(q0t, 1);
        if (last) { VMC(0); } else { VMC(6); }
        BAR(); LGK0();
        __builtin_amdgcn_s_setprio(1);
#pragma unroll
        for (int m = 0; m < 8; ++m) {
            acc[m][2] = __builtin_amdgcn_mfma_f32_16x16x32_bf16(af[m], bk1[2], acc[m][2], 0, 0, 0);
            acc[m][3] = __builtin_amdgcn_mfma_f32_16x16x32_bf16(af[m], bk1[3], acc[m][3], 0, 0, 0);
        }
        __builtin_amdgcn_s_setprio(0);
        BAR();

        // ---------------- tile T1 (buf 1) ----------------
        // ph5
#pragma unroll
        for (int m = 0; m < 8; ++m) af[m] = LDA(1, 0, m);
#pragma unroll
        for (int n = 0; n < 4; ++n) bk0[n] = LDB(1, 0, n);
        stageA(q0t, 1 - 1 + 1); // NT0.A1  (kept explicit below)
        // NOTE: rotation slot ph5 = NT0.A1
        BAR(); LGK0();
        __builtin_amdgcn_s_setprio(1);
#pragma unroll
        for (int m = 0; m < 8; ++m) {
            acc[m][0] = __builtin_amdgcn_mfma_f32_16x16x32_bf16(af[m], bk0[0], acc[m][0], 0, 0, 0);
            acc[m][1] = __builtin_amdgcn_mfma_f32_16x16x32_bf16(af[m], bk0[1], acc[m][1], 0, 0, 0);
        }
        __builtin_amdgcn_s_setprio(0);
        BAR();
        // ph6
#pragma unroll
        for (int n = 0; n < 4; ++n) bk1[n] = LDB(1, 1, n);
        BAR(); LGK0();
        __builtin_amdgcn_s_setprio(1);
#pragma unroll
        for (int m = 0; m < 8; ++m) {
            acc[m][2] = __builtin_amdgcn_mfma_f32_16x16x32_bf16(af[m], bk0[2], acc[m][2], 0, 0, 0);
            acc[m][3] = __builtin_amdgcn_mfma_f32_16x16x32_bf16(af[m], bk0[3], acc[m][3], 0, 0, 0);
        }
        __builtin_amdgcn_s_setprio(0);
        BAR();
        // ph7
#pragma unroll
        for (int m = 0; m < 8; ++m) af[m] = LDA(1, 1, m);
        stageB(q1t, 0); stageB(q1t, 1);
        BAR(); LGK0();
        __builtin_amdgcn_s_setprio(1);
#pragma unroll
        for (int m = 0; m < 8; ++m) {
            acc[m][0] = __builtin_amdgcn_mfma_f32_16x16x32_bf16(af[m], bk1[0], acc[m][0], 0, 0, 0);
            acc[m][1] = __builtin_amdgcn_mfma_f32_16x16x32_bf16(af[m], bk1[1], acc[m][1], 0, 0, 0);
        }
        __builtin_amdgcn_s_setprio(0);
        BAR();
        // ph8
        stageA(q1t, 0);
        if (last) { VMC(0); } else { VMC(6); }
        BAR(); LGK0();
        __builtin_amdgcn_s_setprio(1);
#pragma unroll
        for (int m = 0; m < 8; ++m) {
            acc[m][2] = __builtin_amdgcn_mfma_f32_16x16x32_bf16(af[m], bk1[2], acc[m][2], 0, 0, 0);
            acc[m][3] = __builtin_amdgcn_mfma_f32_16x16x32_bf16(af[m], bk1[3], acc[m][3], 0, 0, 0);
        }
        __builtin_amdgcn_s_setprio(0);
        BAR();
    }

    // epilogue
#pragma unroll
    for (int m = 0; m < 8; ++m) {
        const int row = m0 + wr * 128 + m * 16 + (lane >> 4) * 4;
#pragma unroll
        for (int n = 0; n < 4; ++n) {
            const int col = n0 + wc * 64 + n * 16 + (lane & 15);
            const float bval = bias[col];
#pragma unroll
            for (int r = 0; r < 4; ++r)
                store1(&C[(size_t)(row + r) * N + col], acc[m][n][r] + bval);
        }
    }
}

// ---- 2-phase 128x128 GEMM (proven) — used for the small GEMM2 ----
template <typename CT>
__global__ __launch_bounds__(256)
void gemm2ph(const bf16* __restrict__ A, const bf16* __restrict__ B,
             const float* __restrict__ bias, CT* __restrict__ C,
             int M, int N, int K) {
    __shared__ __align__(16) bf16 As[2][128 * 32];
    __shared__ __align__(16) bf16 Bs[2][128 * 32];

    const int t    = threadIdx.x;
    const int lane = t & 63;
    const int wid  = t >> 6;
    const int wr   = wid >> 1;
    const int wc   = wid & 1;
    const int m0   = blockIdx.y * 128;
    const int n0   = blockIdx.x * 128;

    f32x4 acc[4][4] = {};

    const bf16* gA = A + (size_t)(m0 + wid * 32 + (lane >> 2)) * K + (lane & 3) * 8;
    const bf16* gB = B + (size_t)(n0 + wid * 32 + (lane >> 2)) * K + (lane & 3) * 8;
    const int lofs = wid * 1024;
    const int nt = K / 32;

    gload_lds16(gA, &As[0][lofs]);
    gload_lds16(gA + (size_t)16 * K, &As[0][lofs + 512]);
    gload_lds16(gB, &Bs[0][lofs]);
    gload_lds16(gB + (size_t)16 * K, &Bs[0][lofs + 512]);
    gA += 32; gB += 32;
    __syncthreads();

    int cur = 0;
    for (int tt = 0; tt < nt; ++tt) {
        if (tt + 1 < nt) {
            const int nb = cur ^ 1;
            gload_lds16(gA, &As[nb][lofs]);
            gload_lds16(gA + (size_t)16 * K, &As[nb][lofs + 512]);
            gload_lds16(gB, &Bs[nb][lofs]);
            gload_lds16(gB + (size_t)16 * K, &Bs[nb][lofs + 512]);
            gA += 32; gB += 32;
        }
        bf16x8 af[4], bfr[4];
        const int kb = (lane >> 4) * 16;
#pragma unroll
        for (int i = 0; i < 4; ++i) {
            const int arow = wr * 64 + i * 16 + (lane & 15);
            af[i] = *(const bf16x8*)((const char*)As[cur] + arow * 64 + kb);
            const int brow = wc * 64 + i * 16 + (lane & 15);
            bfr[i] = *(const bf16x8*)((const char*)Bs[cur] + brow * 64 + kb);
        }
#pragma unroll
        for (int i = 0; i < 4; ++i)
#pragma unroll
            for (int j = 0; j < 4; ++j)
                acc[i][j] = __builtin_amdgcn_mfma_f32_16x16x32_bf16(
                    af[i], bfr[j], acc[i][j], 0, 0, 0);
        __syncthreads();
        cur ^= 1;
    }

#pragma unroll
    for (int i = 0; i < 4; ++i) {
        const int row = m0 + wr * 64 + i * 16 + (lane >> 4) * 4;
#pragma unroll
        for (int j = 0; j < 4; ++j) {
            const int col = n0 + wc * 64 + j * 16 + (lane & 15);
            const float bval = bias[col];
#pragma unroll
            for (int r = 0; r < 4; ++r)
                store1(&C[(size_t)(row + r) * N + col], acc[i][j][r] + bval);
        }
    }
}

// ---- fp32 -> bf16 conversion, 4 elems/thread ----
__global__ __launch_bounds__(256)
void cvt_f32_bf16(const float* __restrict__ in, bf16* __restrict__ out, int n4) {
    int i = blockIdx.x * 256 + threadIdx.x;
    if (i >= n4) return;
    float4 v = ((const float4*)in)[i];
    ushort4 o = {f2b(v.x), f2b(v.y), f2b(v.z), f2b(v.w)};
    ((ushort4*)out)[i] = o;
}

// ---- Per-token attention over heads axis + scrambled T write ----
// stride 68 floats (16B-aligned rows, <=2-way banks), float4 everywhere.
__global__ __launch_bounds__(256)
void attn_kernel(const bf16* __restrict__ qkv, bf16* __restrict__ T) {
    __shared__ float lds[4][48 * 68];

    const int wave = threadIdx.x >> 6;
    const int lane = threadIdx.x & 63;
    const int token = blockIdx.x * 4 + wave;
    const int n = token >> 11;
    const int s = token & 2047;

    float* L = lds[wave];
    const bf16* src = qkv + (size_t)token * 3072;

#pragma unroll
    for (int i = 0; i < 6; ++i) {
        int idx = i * 64 + lane;
        uint4 v = *reinterpret_cast<const uint4*>(src + (size_t)idx * 8);
        int e0 = idx * 8;
        float* dst = &L[(e0 >> 6) * 68 + (e0 & 63)];
        float4 a, b;
        a.x = b2f((unsigned short)(v.x & 0xffff));
        a.y = b2f((unsigned short)(v.x >> 16));
        a.z = b2f((unsigned short)(v.y & 0xffff));
        a.w = b2f((unsigned short)(v.y >> 16));
        b.x = b2f((unsigned short)(v.z & 0xffff));
        b.y = b2f((unsigned short)(v.z >> 16));
        b.z = b2f((unsigned short)(v.w & 0xffff));
        b.w = b2f((unsigned short)(v.w >> 16));
        *(float4*)dst = a;
        *(float4*)(dst + 4) = b;
    }
    __syncthreads();

    const int q0 = lane & 15;
    const int g  = lane >> 4;

    float e[4] = {0.f, 0.f, 0.f, 0.f};
    const float* Qr = &L[q0 * 68];
    const float* K0 = &L[(16 + g * 4) * 68];
#pragma unroll
    for (int d = 0; d < 64; d += 4) {
        float4 q4 = *(const float4*)(Qr + d);
#pragma unroll
        for (int j = 0; j < 4; ++j) {
            float4 k4 = *(const float4*)(K0 + j * 68 + d);
            e[j] += q4.x * k4.x + q4.y * k4.y + q4.z * k4.z + q4.w * k4.w;
        }
    }
#pragma unroll
    for (int j = 0; j < 4; ++j) e[j] *= 0.125f;

    float m = fmaxf(fmaxf(e[0], e[1]), fmaxf(e[2], e[3]));
    m = fmaxf(m, __shfl_xor(m, 16));
    m = fmaxf(m, __shfl_xor(m, 32));
    float p[4], sum = 0.f;
#pragma unroll
    for (int j = 0; j < 4; ++j) { p[j] = __expf(e[j] - m); sum += p[j]; }
    sum += __shfl_xor(sum, 16);
    sum += __shfl_xor(sum, 32);
    const float inv = 1.0f / sum;

    float prow[16];
#pragma unroll
    for (int j = 0; j < 4; ++j) {
        prow[g * 4 + j]         = p[j] * inv;
        prow[((g ^ 1) * 4) + j] = __shfl_xor(p[j], 16) * inv;
        prow[((g ^ 2) * 4) + j] = __shfl_xor(p[j], 32) * inv;
        prow[((g ^ 3) * 4) + j] = __shfl_xor(p[j], 48) * inv;
    }

    const int d0 = g * 16;
    float4 o4[4] = {};
#pragma unroll
    for (int k = 0; k < 16; ++k) {
        const float p1 = prow[k];
        const float* Vr = &L[(32 + k) * 68 + d0];
#pragma unroll
        for (int c = 0; c < 4; ++c) {
            float4 v = *(const float4*)(Vr + c * 4);
            o4[c].x += p1 * v.x; o4[c].y += p1 * v.y;
            o4[c].z += p1 * v.z; o4[c].w += p1 * v.w;
        }
    }
    unsigned short outv[16];
#pragma unroll
    for (int c = 0; c < 4; ++c) {
        outv[c * 4 + 0] = f2b(o4[c].x); outv[c * 4 + 1] = f2b(o4[c].y);
        outv[c * 4 + 2] = f2b(o4[c].z); outv[c * 4 + 3] = f2b(o4[c].w);
    }
    const int sp = q0 * 128 + (s >> 4);
    size_t off = ((size_t)n * 2048 + sp) * 1024 + (size_t)(s & 15) * 64 + d0;
    uint4* dst = reinterpret_cast<uint4*>(T + off);
    const uint4* sv = reinterpret_cast<const uint4*>(outv);
    dst[0] = sv[0];
    dst[1] = sv[1];
}

extern "C" void kernel_launch(void* const* d_in, const int* in_sizes, int n_in,
                              void* d_out, int out_size, void* d_ws, size_t ws_size,
                              hipStream_t stream) {
    const float* x     = (const float*)d_in[0];   // (4,2048,1024)
    const float* w_qkv = (const float*)d_in[1];   // (3072,1024)
    const float* b_qkv = (const float*)d_in[2];   // (3072,)
    const float* w_out = (const float*)d_in[3];   // (1024,1024)
    const float* b_out = (const float*)d_in[4];   // (1024,)
    float* out = (float*)d_out;                   // (4,2048,1024) fp32

    const int M = 8192, E = 3072, K = 1024, D = 1024;

    // ws: [0, 50.33M) qkv bf16 -> later W2b; [50.33M, 67.11M) T bf16.
    // d_out doubles as scratch until GEMM2 rewrites it: W1b then X16.
    bf16* qkv = (bf16*)d_ws;
    bf16* T   = qkv + (size_t)M * E;
    bf16* W2b = qkv;
    bf16* W1b = (bf16*)d_out;
    bf16* X16 = W1b + (size_t)E * K;

    dim3 blk(256);

    // 1) x fp32 -> bf16 (d_out scratch)
    cvt_f32_bf16<<<dim3(M * K / 4 / 256), blk, 0, stream>>>(x, X16, M * K / 4);
    // 2) w_qkv fp32 -> bf16 (d_out scratch)
    cvt_f32_bf16<<<dim3(E * K / 4 / 256), blk, 0, stream>>>(w_qkv, W1b, E * K / 4);
    // 3) QKV projection: 256^2 8-phase MFMA -> bf16 qkv
    gemm8p<bf16><<<dim3(E / 256, M / 256), dim3(512), 0, stream>>>(
        X16, W1b, b_qkv, qkv, M, E, K);
    // 4) per-token heads-axis attention + scrambled reshape -> bf16 T
    attn_kernel<<<dim3(M / 4), blk, 0, stream>>>(qkv, T);
    // 5) w_out fp32 -> bf16 (dead qkv region)
    cvt_f32_bf16<<<dim3(D * K / 4 / 256), blk, 0, stream>>>(w_out, W2b, D * K / 4);
    // 6) output projection: 2-phase 128^2 (grid 512 keeps all CUs busy) -> fp32
    gemm2ph<float><<<dim3(D / 128, M / 128), blk, 0, stream>>>(
        T, W2b, b_out, out, M, D, K);
}

// Round 5
// 141.798 us; speedup vs baseline: 1.3026x; 1.3026x over previous
//
#include <hip/hip_runtime.h>
#include <hip/hip_bf16.h>

// N=4, S=2048, D_MODEL=1024, HEADS=16, HEAD_DIM=64. M = 8192 tokens, E = 3072.

typedef __hip_bfloat16 bf16;
using bf16x8 = __attribute__((ext_vector_type(8))) short;
using f32x4  = __attribute__((ext_vector_type(4))) float;

__device__ __forceinline__ float b2f(unsigned short u) {
    return __uint_as_float(((unsigned)u) << 16);
}
__device__ __forceinline__ unsigned short f2b(float f) {
    bf16 h = __float2bfloat16(f);
    return *reinterpret_cast<unsigned short*>(&h);
}
__device__ __forceinline__ void store1(float* p, float v) { *p = v; }
__device__ __forceinline__ void store1(bf16* p, float v) { *p = __float2bfloat16(v); }

// async global->LDS, 16B per lane. LDS dest = wave-uniform base + lane*16.
__device__ __forceinline__ void gload_lds16(const bf16* g, bf16* l) {
    __builtin_amdgcn_global_load_lds(
        (const __attribute__((address_space(1))) void*)g,
        (__attribute__((address_space(3))) void*)l, 16, 0, 0);
}

#define BAR()  __builtin_amdgcn_s_barrier()
#define LGK()  asm volatile("s_waitcnt lgkmcnt(0)" ::: "memory")
#define VMC(N) asm volatile("s_waitcnt vmcnt(" #N ")" ::: "memory")

// one MFMA cluster: 8 m-frags x 2 n-frags, literal NB keeps acc indexing static
#define MFMA_CL(BK, NB)                                                          \
    do {                                                                         \
        __builtin_amdgcn_s_setprio(1);                                           \
        _Pragma("unroll")                                                        \
        for (int m = 0; m < 8; ++m) {                                            \
            acc[m][NB]     = __builtin_amdgcn_mfma_f32_16x16x32_bf16(            \
                af[m], BK[NB], acc[m][NB], 0, 0, 0);                             \
            acc[m][NB + 1] = __builtin_amdgcn_mfma_f32_16x16x32_bf16(            \
                af[m], BK[NB + 1], acc[m][NB + 1], 0, 0, 0);                     \
        }                                                                        \
        __builtin_amdgcn_s_setprio(0);                                           \
    } while (0)

// ============================================================================
// 8-phase 256x256 GEMM. C[M][N] = A[M][K]*B[N][K]^T + bias. K mult of 128.
// 512 thr = 8 waves (2Mx4N), per-wave out 128x64 = acc[8][4] f32x4.
// LDS 128KB, st_16x32 swizzle: linear global_load_lds dest + inverse-swizzled
// GLOBAL k-offset (lane>=32 XOR 16 elems) + XOR-swizzled ds_read (both-sides).
// Stage rotation (one half/phase, all slots read-dead, VMC(4) landing proof):
//   ph1:t1.A0 ph2:t1.A1 ph3:t2.B0 ph4:t2.B1(+VMC4)
//   ph5:t2.A0 ph6:t2.A1 ph7:t3.B0 ph8:t3.B1(+VMC4)
// buf.B read-dead after ph2/ph6; buf.A after ph3/ph7. VMC(4) at ph4 => t1.A
// landed before ph5; at ph8 => t2 landed before next ph1. Last iter: VMC(0).
// ============================================================================
template <typename CT>
__global__ __launch_bounds__(512, 2)
void gemm8p(const bf16* __restrict__ A, const bf16* __restrict__ B,
            const float* __restrict__ bias, CT* __restrict__ C,
            int M, int N, int K) {
    __shared__ alignas(1024) bf16 smem[2][2][16384];  // [buf][A/B][256*64]

    const int t    = threadIdx.x;
    const int lane = t & 63;
    const int wid  = t >> 6;
    const int wr   = wid >> 2;   // 0..1  (M half)
    const int wc   = wid & 3;    // 0..3  (N quarter)
    const int m0   = blockIdx.y * 256;
    const int n0   = blockIdx.x * 256;
    const int nt   = K / 64;
    const int iters = nt / 2;

    // staging source coords (inverse st_16x32 swizzle applied on global k)
    const int srow = wid * 8 + (lane >> 3);                     // 0..63
    const int kel  = ((lane & 7) * 8) ^ ((lane & 32) ? 16 : 0); // elems

    auto stageA = [&](int tt, int h) {
        if (tt >= nt) return;
        bf16* lp = &smem[tt & 1][0][h * 8192 + wid * 512];
        const bf16* gp = A + (size_t)(m0 + h * 128 + srow) * K + tt * 64 + kel;
        gload_lds16(gp, lp);
        gload_lds16(gp + (size_t)64 * K, lp + 4096);
    };
    auto stageB = [&](int tt, int h) {
        if (tt >= nt) return;
        bf16* lp = &smem[tt & 1][1][h * 8192 + wid * 512];
        const bf16* gp = B + (size_t)(n0 + h * 128 + srow) * K + tt * 64 + kel;
        gload_lds16(gp, lp);
        gload_lds16(gp + (size_t)64 * K, lp + 4096);
    };

    // swizzled ds_read of one 16x16x32 fragment
    const int arow_base = wr * 128 + (lane & 15);
    const int brow_base = wc * 64 + (lane & 15);
    const int kqb       = (lane >> 4) * 16;  // k byte sub-offset
    auto LDA = [&](int buf, int kk, int m) -> bf16x8 {
        int ab = (arow_base + m * 16) * 128 + kk * 64 + kqb;
        ab ^= ((ab >> 9) & 1) << 5;
        return *(const bf16x8*)((const char*)&smem[buf][0][0] + ab);
    };
    auto LDB = [&](int buf, int kk, int n) -> bf16x8 {
        int bb = (brow_base + n * 16) * 128 + kk * 64 + kqb;
        bb ^= ((bb >> 9) & 1) << 5;
        return *(const bf16x8*)((const char*)&smem[buf][1][0] + bb);
    };

    f32x4 acc[8][4] = {};
    bf16x8 af[8], bk0[4], bk1[4];

    // prologue: t0 full + t1.B0,B1 (6 halves); wait t0 landed (<=2 halves fly)
    stageB(0, 0); stageB(0, 1); stageA(0, 0); stageA(0, 1);
    stageB(1, 0); stageB(1, 1);
    VMC(4);
    BAR();

    for (int it = 0; it < iters; ++it) {
        const int t1 = 2 * it + 1, t2 = 2 * it + 2, t3 = 2 * it + 3;
        const bool last = (it == iters - 1);

        // ---- tile T0 (buf 0) ----
        // ph1: reads A kk0 (8) + B kk0 (4); stage t1.A0
#pragma unroll
        for (int m = 0; m < 8; ++m) af[m] = LDA(0, 0, m);
#pragma unroll
        for (int n = 0; n < 4; ++n) bk0[n] = LDB(0, 0, n);
        stageA(t1, 0);
        BAR(); LGK();
        MFMA_CL(bk0, 0);
        BAR();
        // ph2: reads B kk1 (4); stage t1.A1
#pragma unroll
        for (int n = 0; n < 4; ++n) bk1[n] = LDB(0, 1, n);
        stageA(t1, 1);
        BAR(); LGK();
        MFMA_CL(bk0, 2);
        BAR();
        // ph3: reads A kk1 (8); stage t2.B0
#pragma unroll
        for (int m = 0; m < 8; ++m) af[m] = LDA(0, 1, m);
        stageB(t2, 0);
        BAR(); LGK();
        MFMA_CL(bk1, 0);
        BAR();
        // ph4: stage t2.B1; counted wait (t1.A landed)
        stageB(t2, 1);
        if (last) { VMC(0); } else { VMC(4); }
        BAR(); LGK();
        MFMA_CL(bk1, 2);
        BAR();

        // ---- tile T1 (buf 1) ----
        // ph5: reads A kk0 + B kk0; stage t2.A0
#pragma unroll
        for (int m = 0; m < 8; ++m) af[m] = LDA(1, 0, m);
#pragma unroll
        for (int n = 0; n < 4; ++n) bk0[n] = LDB(1, 0, n);
        stageA(t2, 0);
        BAR(); LGK();
        MFMA_CL(bk0, 0);
        BAR();
        // ph6: reads B kk1; stage t2.A1
#pragma unroll
        for (int n = 0; n < 4; ++n) bk1[n] = LDB(1, 1, n);
        stageA(t2, 1);
        BAR(); LGK();
        MFMA_CL(bk0, 2);
        BAR();
        // ph7: reads A kk1; stage t3.B0
#pragma unroll
        for (int m = 0; m < 8; ++m) af[m] = LDA(1, 1, m);
        stageB(t3, 0);
        BAR(); LGK();
        MFMA_CL(bk1, 0);
        BAR();
        // ph8: stage t3.B1; counted wait (t2 landed)
        stageB(t3, 1);
        if (last) { VMC(0); } else { VMC(4); }
        BAR(); LGK();
        MFMA_CL(bk1, 2);
        BAR();
    }

    // epilogue
#pragma unroll
    for (int m = 0; m < 8; ++m) {
        const int row = m0 + wr * 128 + m * 16 + (lane >> 4) * 4;
#pragma unroll
        for (int n = 0; n < 4; ++n) {
            const int col = n0 + wc * 64 + n * 16 + (lane & 15);
            const float bval = bias[col];
#pragma unroll
            for (int r = 0; r < 4; ++r)
                store1(&C[(size_t)(row + r) * N + col], acc[m][n][r] + bval);
        }
    }
}

// ---- 2-phase 128x128 GEMM (proven) — used for the small GEMM2 ----
template <typename CT>
__global__ __launch_bounds__(256)
void gemm2ph(const bf16* __restrict__ A, const bf16* __restrict__ B,
             const float* __restrict__ bias, CT* __restrict__ C,
             int M, int N, int K) {
    __shared__ __align__(16) bf16 As[2][128 * 32];
    __shared__ __align__(16) bf16 Bs[2][128 * 32];

    const int t    = threadIdx.x;
    const int lane = t & 63;
    const int wid  = t >> 6;
    const int wr   = wid >> 1;
    const int wc   = wid & 1;
    const int m0   = blockIdx.y * 128;
    const int n0   = blockIdx.x * 128;

    f32x4 acc[4][4] = {};

    const bf16* gA = A + (size_t)(m0 + wid * 32 + (lane >> 2)) * K + (lane & 3) * 8;
    const bf16* gB = B + (size_t)(n0 + wid * 32 + (lane >> 2)) * K + (lane & 3) * 8;
    const int lofs = wid * 1024;
    const int nt = K / 32;

    gload_lds16(gA, &As[0][lofs]);
    gload_lds16(gA + (size_t)16 * K, &As[0][lofs + 512]);
    gload_lds16(gB, &Bs[0][lofs]);
    gload_lds16(gB + (size_t)16 * K, &Bs[0][lofs + 512]);
    gA += 32; gB += 32;
    __syncthreads();

    int cur = 0;
    for (int tt = 0; tt < nt; ++tt) {
        if (tt + 1 < nt) {
            const int nb = cur ^ 1;
            gload_lds16(gA, &As[nb][lofs]);
            gload_lds16(gA + (size_t)16 * K, &As[nb][lofs + 512]);
            gload_lds16(gB, &Bs[nb][lofs]);
            gload_lds16(gB + (size_t)16 * K, &Bs[nb][lofs + 512]);
            gA += 32; gB += 32;
        }
        bf16x8 af[4], bfr[4];
        const int kb = (lane >> 4) * 16;
#pragma unroll
        for (int i = 0; i < 4; ++i) {
            const int arow = wr * 64 + i * 16 + (lane & 15);
            af[i] = *(const bf16x8*)((const char*)As[cur] + arow * 64 + kb);
            const int brow = wc * 64 + i * 16 + (lane & 15);
            bfr[i] = *(const bf16x8*)((const char*)Bs[cur] + brow * 64 + kb);
        }
#pragma unroll
        for (int i = 0; i < 4; ++i)
#pragma unroll
            for (int j = 0; j < 4; ++j)
                acc[i][j] = __builtin_amdgcn_mfma_f32_16x16x32_bf16(
                    af[i], bfr[j], acc[i][j], 0, 0, 0);
        __syncthreads();
        cur ^= 1;
    }

#pragma unroll
    for (int i = 0; i < 4; ++i) {
        const int row = m0 + wr * 64 + i * 16 + (lane >> 4) * 4;
#pragma unroll
        for (int j = 0; j < 4; ++j) {
            const int col = n0 + wc * 64 + j * 16 + (lane & 15);
            const float bval = bias[col];
#pragma unroll
            for (int r = 0; r < 4; ++r)
                store1(&C[(size_t)(row + r) * N + col], acc[i][j][r] + bval);
        }
    }
}

// ---- fp32 -> bf16 conversion, 4 elems/thread ----
__global__ __launch_bounds__(256)
void cvt_f32_bf16(const float* __restrict__ in, bf16* __restrict__ out, int n4) {
    int i = blockIdx.x * 256 + threadIdx.x;
    if (i >= n4) return;
    float4 v = ((const float4*)in)[i];
    ushort4 o = {f2b(v.x), f2b(v.y), f2b(v.z), f2b(v.w)};
    ((ushort4*)out)[i] = o;
}

// ---- Per-token attention over heads axis + scrambled T write ----
// stride 68 floats (16B-aligned rows, <=2-way banks), float4 everywhere.
__global__ __launch_bounds__(256)
void attn_kernel(const bf16* __restrict__ qkv, bf16* __restrict__ T) {
    __shared__ float lds[4][48 * 68];

    const int wave = threadIdx.x >> 6;
    const int lane = threadIdx.x & 63;
    const int token = blockIdx.x * 4 + wave;
    const int n = token >> 11;
    const int s = token & 2047;

    float* L = lds[wave];
    const bf16* src = qkv + (size_t)token * 3072;

#pragma unroll
    for (int i = 0; i < 6; ++i) {
        int idx = i * 64 + lane;
        uint4 v = *reinterpret_cast<const uint4*>(src + (size_t)idx * 8);
        int e0 = idx * 8;
        float* dst = &L[(e0 >> 6) * 68 + (e0 & 63)];
        float4 a, b;
        a.x = b2f((unsigned short)(v.x & 0xffff));
        a.y = b2f((unsigned short)(v.x >> 16));
        a.z = b2f((unsigned short)(v.y & 0xffff));
        a.w = b2f((unsigned short)(v.y >> 16));
        b.x = b2f((unsigned short)(v.z & 0xffff));
        b.y = b2f((unsigned short)(v.z >> 16));
        b.z = b2f((unsigned short)(v.w & 0xffff));
        b.w = b2f((unsigned short)(v.w >> 16));
        *(float4*)dst = a;
        *(float4*)(dst + 4) = b;
    }
    __syncthreads();

    const int q0 = lane & 15;
    const int g  = lane >> 4;

    float e[4] = {0.f, 0.f, 0.f, 0.f};
    const float* Qr = &L[q0 * 68];
    const float* K0 = &L[(16 + g * 4) * 68];
#pragma unroll
    for (int d = 0; d < 64; d += 4) {
        float4 q4 = *(const float4*)(Qr + d);
#pragma unroll
        for (int j = 0; j < 4; ++j) {
            float4 k4 = *(const float4*)(K0 + j * 68 + d);
            e[j] += q4.x * k4.x + q4.y * k4.y + q4.z * k4.z + q4.w * k4.w;
        }
    }
#pragma unroll
    for (int j = 0; j < 4; ++j) e[j] *= 0.125f;

    float m = fmaxf(fmaxf(e[0], e[1]), fmaxf(e[2], e[3]));
    m = fmaxf(m, __shfl_xor(m, 16));
    m = fmaxf(m, __shfl_xor(m, 32));
    float p[4], sum = 0.f;
#pragma unroll
    for (int j = 0; j < 4; ++j) { p[j] = __expf(e[j] - m); sum += p[j]; }
    sum += __shfl_xor(sum, 16);
    sum += __shfl_xor(sum, 32);
    const float inv = 1.0f / sum;

    float prow[16];
#pragma unroll
    for (int j = 0; j < 4; ++j) {
        prow[g * 4 + j]         = p[j] * inv;
        prow[((g ^ 1) * 4) + j] = __shfl_xor(p[j], 16) * inv;
        prow[((g ^ 2) * 4) + j] = __shfl_xor(p[j], 32) * inv;
        prow[((g ^ 3) * 4) + j] = __shfl_xor(p[j], 48) * inv;
    }

    const int d0 = g * 16;
    float4 o4[4] = {};
#pragma unroll
    for (int k = 0; k < 16; ++k) {
        const float p1 = prow[k];
        const float* Vr = &L[(32 + k) * 68 + d0];
#pragma unroll
        for (int c = 0; c < 4; ++c) {
            float4 v = *(const float4*)(Vr + c * 4);
            o4[c].x += p1 * v.x; o4[c].y += p1 * v.y;
            o4[c].z += p1 * v.z; o4[c].w += p1 * v.w;
        }
    }
    unsigned short outv[16];
#pragma unroll
    for (int c = 0; c < 4; ++c) {
        outv[c * 4 + 0] = f2b(o4[c].x); outv[c * 4 + 1] = f2b(o4[c].y);
        outv[c * 4 + 2] = f2b(o4[c].z); outv[c * 4 + 3] = f2b(o4[c].w);
    }
    const int sp = q0 * 128 + (s >> 4);
    size_t off = ((size_t)n * 2048 + sp) * 1024 + (size_t)(s & 15) * 64 + d0;
    uint4* dst = reinterpret_cast<uint4*>(T + off);
    const uint4* sv = reinterpret_cast<const uint4*>(outv);
    dst[0] = sv[0];
    dst[1] = sv[1];
}

extern "C" void kernel_launch(void* const* d_in, const int* in_sizes, int n_in,
                              void* d_out, int out_size, void* d_ws, size_t ws_size,
                              hipStream_t stream) {
    const float* x     = (const float*)d_in[0];   // (4,2048,1024)
    const float* w_qkv = (const float*)d_in[1];   // (3072,1024)
    const float* b_qkv = (const float*)d_in[2];   // (3072,)
    const float* w_out = (const float*)d_in[3];   // (1024,1024)
    const float* b_out = (const float*)d_in[4];   // (1024,)
    float* out = (float*)d_out;                   // (4,2048,1024) fp32

    const int M = 8192, E = 3072, K = 1024, D = 1024;

    // ws: [0, 50.33M) qkv bf16 -> later W2b; [50.33M, 67.11M) T bf16.
    // d_out doubles as scratch until GEMM2 rewrites it: W1b then X16.
    bf16* qkv = (bf16*)d_ws;
    bf16* T   = qkv + (size_t)M * E;
    bf16* W2b = qkv;
    bf16* W1b = (bf16*)d_out;
    bf16* X16 = W1b + (size_t)E * K;

    dim3 blk(256);

    // 1) x fp32 -> bf16 (d_out scratch)
    cvt_f32_bf16<<<dim3(M * K / 4 / 256), blk, 0, stream>>>(x, X16, M * K / 4);
    // 2) w_qkv fp32 -> bf16 (d_out scratch)
    cvt_f32_bf16<<<dim3(E * K / 4 / 256), blk, 0, stream>>>(w_qkv, W1b, E * K / 4);
    // 3) QKV projection: 256^2 8-phase MFMA -> bf16 qkv
    gemm8p<bf16><<<dim3(E / 256, M / 256), dim3(512), 0, stream>>>(
        X16, W1b, b_qkv, qkv, M, E, K);
    // 4) per-token heads-axis attention + scrambled reshape -> bf16 T
    attn_kernel<<<dim3(M / 4), blk, 0, stream>>>(qkv, T);
    // 5) w_out fp32 -> bf16 (dead qkv region)
    cvt_f32_bf16<<<dim3(D * K / 4 / 256), blk, 0, stream>>>(w_out, W2b, D * K / 4);
    // 6) output projection: 2-phase 128^2 (grid 512 keeps all CUs busy) -> fp32
    gemm2ph<float><<<dim3(D / 128, M / 128), blk, 0, stream>>>(
        T, W2b, b_out, out, M, D, K);
}

// Round 6
// 137.903 us; speedup vs baseline: 1.3394x; 1.0282x over previous
//
#include <hip/hip_runtime.h>
#include <hip/hip_bf16.h>

// N=4, S=2048, D_MODEL=1024, HEADS=16, HEAD_DIM=64. M = 8192 tokens, E = 3072.

typedef __hip_bfloat16 bf16;
using bf16x8 = __attribute__((ext_vector_type(8))) short;
using f32x4  = __attribute__((ext_vector_type(4))) float;

__device__ __forceinline__ float b2f(unsigned short u) {
    return __uint_as_float(((unsigned)u) << 16);
}
__device__ __forceinline__ unsigned short f2b(float f) {
    bf16 h = __float2bfloat16(f);
    return *reinterpret_cast<unsigned short*>(&h);
}
__device__ __forceinline__ void store1(float* p, float v) { *p = v; }
__device__ __forceinline__ void store1(bf16* p, float v) { *p = __float2bfloat16(v); }

// async global->LDS, 16B per lane. LDS dest = wave-uniform base + lane*16.
__device__ __forceinline__ void gload_lds16(const bf16* g, bf16* l) {
    __builtin_amdgcn_global_load_lds(
        (const __attribute__((address_space(1))) void*)g,
        (__attribute__((address_space(3))) void*)l, 16, 0, 0);
}

// ---- 2-phase MFMA GEMM: C[M][N] = A[M][K] * B[N][K]^T + bias[N] ----
// BM=128 fixed, BN template (128 or 64). 256 thr = 4 waves (2x2).
// Per-wave out: 64 x BN/2 -> acc[4][BN/32]. BK=32 double-buffered,
// prefetch tile t+1 via global_load_lds BEFORE computing tile t.
// BN=128: grid-rich GEMMs (3+ blocks/CU). BN=64: small-N GEMMs needing
// more resident blocks for latency hiding (24KB LDS -> 4+ blocks/CU).
template <int BN, typename CT>
__global__ __launch_bounds__(256)
void gemm2ph(const bf16* __restrict__ A, const bf16* __restrict__ B,
             const float* __restrict__ bias, CT* __restrict__ C,
             int M, int N, int K) {
    constexpr int NF = BN / 32;         // n-frags per wave
    constexpr int BROWS = BN / 4;       // B rows staged per wave
    __shared__ __align__(16) bf16 As[2][128 * 32];
    __shared__ __align__(16) bf16 Bs[2][BN * 32];

    const int t    = threadIdx.x;
    const int lane = t & 63;
    const int wid  = t >> 6;
    const int wr   = wid >> 1;
    const int wc   = wid & 1;
    const int m0   = blockIdx.y * 128;
    const int n0   = blockIdx.x * BN;

    f32x4 acc[4][NF] = {};

    const bf16* gA = A + (size_t)(m0 + wid * 32 + (lane >> 2)) * K + (lane & 3) * 8;
    const bf16* gB = B + (size_t)(n0 + wid * BROWS + (lane >> 2)) * K + (lane & 3) * 8;
    const int aofs = wid * 1024;        // wave's A region (32 rows * 32 k)
    const int bofs = wid * BROWS * 32;  // wave's B region
    const int nt = K / 32;

    auto stage = [&](int buf) {
        gload_lds16(gA, &As[buf][aofs]);
        gload_lds16(gA + (size_t)16 * K, &As[buf][aofs + 512]);
#pragma unroll
        for (int i = 0; i < BN / 64; ++i)
            gload_lds16(gB + (size_t)i * 16 * K, &Bs[buf][bofs + i * 512]);
        gA += 32; gB += 32;
    };

    stage(0);
    __syncthreads();

    int cur = 0;
    for (int tt = 0; tt < nt; ++tt) {
        if (tt + 1 < nt) stage(cur ^ 1);

        bf16x8 af[4], bfr[NF];
        const int kb = (lane >> 4) * 16;
#pragma unroll
        for (int i = 0; i < 4; ++i) {
            const int arow = wr * 64 + i * 16 + (lane & 15);
            af[i] = *(const bf16x8*)((const char*)As[cur] + arow * 64 + kb);
        }
#pragma unroll
        for (int j = 0; j < NF; ++j) {
            const int brow = wc * (BN / 2) + j * 16 + (lane & 15);
            bfr[j] = *(const bf16x8*)((const char*)Bs[cur] + brow * 64 + kb);
        }
#pragma unroll
        for (int i = 0; i < 4; ++i)
#pragma unroll
            for (int j = 0; j < NF; ++j)
                acc[i][j] = __builtin_amdgcn_mfma_f32_16x16x32_bf16(
                    af[i], bfr[j], acc[i][j], 0, 0, 0);
        __syncthreads();
        cur ^= 1;
    }

#pragma unroll
    for (int i = 0; i < 4; ++i) {
        const int row = m0 + wr * 64 + i * 16 + (lane >> 4) * 4;
#pragma unroll
        for (int j = 0; j < NF; ++j) {
            const int col = n0 + wc * (BN / 2) + j * 16 + (lane & 15);
            const float bval = bias[col];
#pragma unroll
            for (int r = 0; r < 4; ++r)
                store1(&C[(size_t)(row + r) * N + col], acc[i][j][r] + bval);
        }
    }
}

// ---- fp32 -> bf16 conversion, 4 elems/thread ----
__global__ __launch_bounds__(256)
void cvt_f32_bf16(const float* __restrict__ in, bf16* __restrict__ out, int n4) {
    int i = blockIdx.x * 256 + threadIdx.x;
    if (i >= n4) return;
    float4 v = ((const float4*)in)[i];
    ushort4 o = {f2b(v.x), f2b(v.y), f2b(v.z), f2b(v.w)};
    ((ushort4*)out)[i] = o;
}

// ---- Per-token attention over heads axis + scrambled T write ----
// stride 68 floats (16B-aligned rows, <=2-way banks), float4 everywhere.
__global__ __launch_bounds__(256)
void attn_kernel(const bf16* __restrict__ qkv, bf16* __restrict__ T) {
    __shared__ float lds[4][48 * 68];

    const int wave = threadIdx.x >> 6;
    const int lane = threadIdx.x & 63;
    const int token = blockIdx.x * 4 + wave;
    const int n = token >> 11;
    const int s = token & 2047;

    float* L = lds[wave];
    const bf16* src = qkv + (size_t)token * 3072;

#pragma unroll
    for (int i = 0; i < 6; ++i) {
        int idx = i * 64 + lane;
        uint4 v = *reinterpret_cast<const uint4*>(src + (size_t)idx * 8);
        int e0 = idx * 8;
        float* dst = &L[(e0 >> 6) * 68 + (e0 & 63)];
        float4 a, b;
        a.x = b2f((unsigned short)(v.x & 0xffff));
        a.y = b2f((unsigned short)(v.x >> 16));
        a.z = b2f((unsigned short)(v.y & 0xffff));
        a.w = b2f((unsigned short)(v.y >> 16));
        b.x = b2f((unsigned short)(v.z & 0xffff));
        b.y = b2f((unsigned short)(v.z >> 16));
        b.z = b2f((unsigned short)(v.w & 0xffff));
        b.w = b2f((unsigned short)(v.w >> 16));
        *(float4*)dst = a;
        *(float4*)(dst + 4) = b;
    }
    __syncthreads();

    const int q0 = lane & 15;
    const int g  = lane >> 4;

    float e[4] = {0.f, 0.f, 0.f, 0.f};
    const float* Qr = &L[q0 * 68];
    const float* K0 = &L[(16 + g * 4) * 68];
#pragma unroll
    for (int d = 0; d < 64; d += 4) {
        float4 q4 = *(const float4*)(Qr + d);
#pragma unroll
        for (int j = 0; j < 4; ++j) {
            float4 k4 = *(const float4*)(K0 + j * 68 + d);
            e[j] += q4.x * k4.x + q4.y * k4.y + q4.z * k4.z + q4.w * k4.w;
        }
    }
#pragma unroll
    for (int j = 0; j < 4; ++j) e[j] *= 0.125f;

    float m = fmaxf(fmaxf(e[0], e[1]), fmaxf(e[2], e[3]));
    m = fmaxf(m, __shfl_xor(m, 16));
    m = fmaxf(m, __shfl_xor(m, 32));
    float p[4], sum = 0.f;
#pragma unroll
    for (int j = 0; j < 4; ++j) { p[j] = __expf(e[j] - m); sum += p[j]; }
    sum += __shfl_xor(sum, 16);
    sum += __shfl_xor(sum, 32);
    const float inv = 1.0f / sum;

    float prow[16];
#pragma unroll
    for (int j = 0; j < 4; ++j) {
        prow[g * 4 + j]         = p[j] * inv;
        prow[((g ^ 1) * 4) + j] = __shfl_xor(p[j], 16) * inv;
        prow[((g ^ 2) * 4) + j] = __shfl_xor(p[j], 32) * inv;
        prow[((g ^ 3) * 4) + j] = __shfl_xor(p[j], 48) * inv;
    }

    const int d0 = g * 16;
    float4 o4[4] = {};
#pragma unroll
    for (int k = 0; k < 16; ++k) {
        const float p1 = prow[k];
        const float* Vr = &L[(32 + k) * 68 + d0];
#pragma unroll
        for (int c = 0; c < 4; ++c) {
            float4 v = *(const float4*)(Vr + c * 4);
            o4[c].x += p1 * v.x; o4[c].y += p1 * v.y;
            o4[c].z += p1 * v.z; o4[c].w += p1 * v.w;
        }
    }
    unsigned short outv[16];
#pragma unroll
    for (int c = 0; c < 4; ++c) {
        outv[c * 4 + 0] = f2b(o4[c].x); outv[c * 4 + 1] = f2b(o4[c].y);
        outv[c * 4 + 2] = f2b(o4[c].z); outv[c * 4 + 3] = f2b(o4[c].w);
    }
    const int sp = q0 * 128 + (s >> 4);
    size_t off = ((size_t)n * 2048 + sp) * 1024 + (size_t)(s & 15) * 64 + d0;
    uint4* dst = reinterpret_cast<uint4*>(T + off);
    const uint4* sv = reinterpret_cast<const uint4*>(outv);
    dst[0] = sv[0];
    dst[1] = sv[1];
}

extern "C" void kernel_launch(void* const* d_in, const int* in_sizes, int n_in,
                              void* d_out, int out_size, void* d_ws, size_t ws_size,
                              hipStream_t stream) {
    const float* x     = (const float*)d_in[0];   // (4,2048,1024)
    const float* w_qkv = (const float*)d_in[1];   // (3072,1024)
    const float* b_qkv = (const float*)d_in[2];   // (3072,)
    const float* w_out = (const float*)d_in[3];   // (1024,1024)
    const float* b_out = (const float*)d_in[4];   // (1024,)
    float* out = (float*)d_out;                   // (4,2048,1024) fp32

    const int M = 8192, E = 3072, K = 1024, D = 1024;

    // ws: [0, 50.33M) qkv bf16 -> later W2b; [50.33M, 67.11M) T bf16.
    // d_out doubles as scratch until GEMM2 rewrites it: W1b then X16.
    bf16* qkv = (bf16*)d_ws;
    bf16* T   = qkv + (size_t)M * E;
    bf16* W2b = qkv;
    bf16* W1b = (bf16*)d_out;
    bf16* X16 = W1b + (size_t)E * K;

    dim3 blk(256);

    // 1) x fp32 -> bf16 (d_out scratch)
    cvt_f32_bf16<<<dim3(M * K / 4 / 256), blk, 0, stream>>>(x, X16, M * K / 4);
    // 2) w_qkv fp32 -> bf16 (d_out scratch)
    cvt_f32_bf16<<<dim3(E * K / 4 / 256), blk, 0, stream>>>(w_qkv, W1b, E * K / 4);
    // 3) QKV projection: proven 2-phase 128x128 (768 blocks = 3/CU) -> bf16 qkv
    gemm2ph<128, bf16><<<dim3(E / 128, M / 128), blk, 0, stream>>>(
        X16, W1b, b_qkv, qkv, M, E, K);
    // 4) per-token heads-axis attention + scrambled reshape -> bf16 T
    attn_kernel<<<dim3(M / 4), blk, 0, stream>>>(qkv, T);
    // 5) w_out fp32 -> bf16 (dead qkv region)
    cvt_f32_bf16<<<dim3(D * K / 4 / 256), blk, 0, stream>>>(w_out, W2b, D * K / 4);
    // 6) output projection: 128x64 tiles (1024 blocks = 4/CU for TLP) -> fp32
    gemm2ph<64, float><<<dim3(D / 64, M / 128), blk, 0, stream>>>(
        T, W2b, b_out, out, M, D, K);
}

// Round 7
// 137.743 us; speedup vs baseline: 1.3410x; 1.0012x over previous
//
#include <hip/hip_runtime.h>
#include <hip/hip_bf16.h>

// N=4, S=2048, D_MODEL=1024, HEADS=16, HEAD_DIM=64. M = 8192 tokens, E = 3072.

typedef __hip_bfloat16 bf16;
using bf16x8 = __attribute__((ext_vector_type(8))) short;
using f32x4  = __attribute__((ext_vector_type(4))) float;

__device__ __forceinline__ float b2f(unsigned short u) {
    return __uint_as_float(((unsigned)u) << 16);
}
__device__ __forceinline__ unsigned short f2b(float f) {
    bf16 h = __float2bfloat16(f);
    return *reinterpret_cast<unsigned short*>(&h);
}
__device__ __forceinline__ void store1(float* p, float v) { *p = v; }
__device__ __forceinline__ void store1(bf16* p, float v) { *p = __float2bfloat16(v); }

// async global->LDS, 16B per lane. LDS dest = wave-uniform base + lane*16.
__device__ __forceinline__ void gload_lds16(const bf16* g, bf16* l) {
    __builtin_amdgcn_global_load_lds(
        (const __attribute__((address_space(1))) void*)g,
        (__attribute__((address_space(3))) void*)l, 16, 0, 0);
}

#define BAR()  __builtin_amdgcn_s_barrier()
#define LGK()  asm volatile("s_waitcnt lgkmcnt(0)" ::: "memory")
#define VMC(N) asm volatile("s_waitcnt vmcnt(" #N ")" ::: "memory")

// one MFMA cluster: 8 m-frags x 2 n-frags, literal NB keeps acc indexing static
#define MFMA_CL(BK, NB)                                                          \
    do {                                                                         \
        __builtin_amdgcn_s_setprio(1);                                           \
        _Pragma("unroll")                                                        \
        for (int m = 0; m < 8; ++m) {                                            \
            acc[m][NB]     = __builtin_amdgcn_mfma_f32_16x16x32_bf16(            \
                af[m], BK[NB], acc[m][NB], 0, 0, 0);                             \
            acc[m][NB + 1] = __builtin_amdgcn_mfma_f32_16x16x32_bf16(            \
                af[m], BK[NB + 1], acc[m][NB + 1], 0, 0, 0);                     \
        }                                                                        \
        __builtin_amdgcn_s_setprio(0);                                           \
    } while (0)

// ============================================================================
// 8-phase 256x256 GEMM. C[M][N] = A[M][K]*B[N][K]^T + bias. K mult of 128.
// 512 thr = 8 waves (2Mx4N), per-wave out 128x64 = acc[8][4] f32x4.
// LDS 128KB. Bank-conflict swizzle for 128B rows (G4 geometry, NOT st_16x32):
//   read byte addr ^= (row&7)<<4  (16 rows -> 8 distinct 16B slots = 32 banks,
//   2-way residual = free). Inverse applied on GLOBAL source k-offset:
//   kel = ((lane&7) ^ (lane>>3)) * 8 elems  (dest row&7 == lane>>3, involution).
// Stage rotation (one half/phase; each slot read-dead; vmcnt counts 2/stage):
//   ph1:t1.A0 ph2:t1.A1 ph3:t2.B0 ph4:t2.B1(+VMC4)
//   ph5:t2.A0 ph6:t2.A1 ph7:t3.B0 ph8:t3.B1(+VMC4)
// VMC(4) at ph4 => t1 fully landed before ph5; at ph8 => t2 landed before
// next ph1. Last iter: VMC(0). XCD-aware block remap (grid%8==0, bijective).
// ============================================================================
template <typename CT>
__global__ __launch_bounds__(512, 2)
void gemm8p(const bf16* __restrict__ A, const bf16* __restrict__ B,
            const float* __restrict__ bias, CT* __restrict__ C,
            int M, int N, int K, int gx) {
    __shared__ alignas(1024) bf16 smem[2][2][16384];  // [buf][A/B][256 rows*64]

    const int t    = threadIdx.x;
    const int lane = t & 63;
    const int wid  = t >> 6;
    const int wr   = wid >> 2;   // 0..1  (M half)
    const int wc   = wid & 3;    // 0..3  (N quarter)

    // XCD-aware bijective remap (gridDim.x % 8 == 0)
    const int nwg = gridDim.x;
    const int bid = blockIdx.x;
    const int wg  = (bid & 7) * (nwg >> 3) + (bid >> 3);
    const int m0  = (wg / gx) * 256;
    const int n0  = (wg % gx) * 256;

    const int nt   = K / 64;
    const int iters = nt / 2;

    // staging coords: dest row = wid*8 + (lane>>3) (+64 for 2nd load);
    // source k pre-swizzled so read-side XOR recovers linear k.
    const int srow = wid * 8 + (lane >> 3);                  // 0..63
    const int kel  = (((lane & 7) ^ (lane >> 3))) * 8;       // inverse swizzle

    auto stageA = [&](int tt, int h) {
        if (tt >= nt) return;
        bf16* lp = &smem[tt & 1][0][h * 8192 + wid * 512];
        const bf16* gp = A + (size_t)(m0 + h * 128 + srow) * K + tt * 64 + kel;
        gload_lds16(gp, lp);
        gload_lds16(gp + (size_t)64 * K, lp + 4096);
    };
    auto stageB = [&](int tt, int h) {
        if (tt >= nt) return;
        bf16* lp = &smem[tt & 1][1][h * 8192 + wid * 512];
        const bf16* gp = B + (size_t)(n0 + h * 128 + srow) * K + tt * 64 + kel;
        gload_lds16(gp, lp);
        gload_lds16(gp + (size_t)64 * K, lp + 4096);
    };

    // swizzled ds_read of one 16x16x32 fragment (row*128B + k-byte, G4 XOR)
    const int arow_base = wr * 128 + (lane & 15);
    const int brow_base = wc * 64 + (lane & 15);
    const int kqb       = (lane >> 4) * 16;  // k byte sub-offset
    auto LDA = [&](int buf, int kk, int m) -> bf16x8 {
        const int row = arow_base + m * 16;
        int ab = row * 128 + ((kk * 64 + kqb) ^ ((row & 7) << 4));
        return *(const bf16x8*)((const char*)&smem[buf][0][0] + ab);
    };
    auto LDB = [&](int buf, int kk, int n) -> bf16x8 {
        const int row = brow_base + n * 16;
        int bb = row * 128 + ((kk * 64 + kqb) ^ ((row & 7) << 4));
        return *(const bf16x8*)((const char*)&smem[buf][1][0] + bb);
    };

    f32x4 acc[8][4] = {};
    bf16x8 af[8], bk0[4], bk1[4];

    // prologue: t0 full + t1.B0,B1 (12 loads); VMC(4) => t0 landed
    stageB(0, 0); stageB(0, 1); stageA(0, 0); stageA(0, 1);
    stageB(1, 0); stageB(1, 1);
    VMC(4);
    BAR();

    for (int it = 0; it < iters; ++it) {
        const int t1 = 2 * it + 1, t2 = 2 * it + 2, t3 = 2 * it + 3;
        const bool last = (it == iters - 1);

        // ---- tile T0 (buf 0) ----
        // ph1: reads A kk0 (8) + B kk0 (4); stage t1.A0
#pragma unroll
        for (int m = 0; m < 8; ++m) af[m] = LDA(0, 0, m);
#pragma unroll
        for (int n = 0; n < 4; ++n) bk0[n] = LDB(0, 0, n);
        stageA(t1, 0);
        BAR(); LGK();
        MFMA_CL(bk0, 0);
        BAR();
        // ph2: reads B kk1 (4); stage t1.A1
#pragma unroll
        for (int n = 0; n < 4; ++n) bk1[n] = LDB(0, 1, n);
        stageA(t1, 1);
        BAR(); LGK();
        MFMA_CL(bk0, 2);
        BAR();
        // ph3: reads A kk1 (8); stage t2.B0
#pragma unroll
        for (int m = 0; m < 8; ++m) af[m] = LDA(0, 1, m);
        stageB(t2, 0);
        BAR(); LGK();
        MFMA_CL(bk1, 0);
        BAR();
        // ph4: stage t2.B1; counted wait (t1 landed)
        stageB(t2, 1);
        if (last) { VMC(0); } else { VMC(4); }
        BAR(); LGK();
        MFMA_CL(bk1, 2);
        BAR();

        // ---- tile T1 (buf 1) ----
        // ph5: reads A kk0 + B kk0; stage t2.A0
#pragma unroll
        for (int m = 0; m < 8; ++m) af[m] = LDA(1, 0, m);
#pragma unroll
        for (int n = 0; n < 4; ++n) bk0[n] = LDB(1, 0, n);
        stageA(t2, 0);
        BAR(); LGK();
        MFMA_CL(bk0, 0);
        BAR();
        // ph6: reads B kk1; stage t2.A1
#pragma unroll
        for (int n = 0; n < 4; ++n) bk1[n] = LDB(1, 1, n);
        stageA(t2, 1);
        BAR(); LGK();
        MFMA_CL(bk0, 2);
        BAR();
        // ph7: reads A kk1; stage t3.B0
#pragma unroll
        for (int m = 0; m < 8; ++m) af[m] = LDA(1, 1, m);
        stageB(t3, 0);
        BAR(); LGK();
        MFMA_CL(bk1, 0);
        BAR();
        // ph8: stage t3.B1; counted wait (t2 landed)
        stageB(t3, 1);
        if (last) { VMC(0); } else { VMC(4); }
        BAR(); LGK();
        MFMA_CL(bk1, 2);
        BAR();
    }

    // epilogue
#pragma unroll
    for (int m = 0; m < 8; ++m) {
        const int row = m0 + wr * 128 + m * 16 + (lane >> 4) * 4;
#pragma unroll
        for (int n = 0; n < 4; ++n) {
            const int col = n0 + wc * 64 + n * 16 + (lane & 15);
            const float bval = bias[col];
#pragma unroll
            for (int r = 0; r < 4; ++r)
                store1(&C[(size_t)(row + r) * N + col], acc[m][n][r] + bval);
        }
    }
}

// ---- fp32 -> bf16 conversion, 4 elems/thread ----
__global__ __launch_bounds__(256)
void cvt_f32_bf16(const float* __restrict__ in, bf16* __restrict__ out, int n4) {
    int i = blockIdx.x * 256 + threadIdx.x;
    if (i >= n4) return;
    float4 v = ((const float4*)in)[i];
    ushort4 o = {f2b(v.x), f2b(v.y), f2b(v.z), f2b(v.w)};
    ((ushort4*)out)[i] = o;
}

// ---- Per-token attention over heads axis + scrambled T write ----
// stride 68 floats (16B-aligned rows, <=2-way banks), float4 everywhere.
__global__ __launch_bounds__(256)
void attn_kernel(const bf16* __restrict__ qkv, bf16* __restrict__ T) {
    __shared__ float lds[4][48 * 68];

    const int wave = threadIdx.x >> 6;
    const int lane = threadIdx.x & 63;
    const int token = blockIdx.x * 4 + wave;
    const int n = token >> 11;
    const int s = token & 2047;

    float* L = lds[wave];
    const bf16* src = qkv + (size_t)token * 3072;

#pragma unroll
    for (int i = 0; i < 6; ++i) {
        int idx = i * 64 + lane;
        uint4 v = *reinterpret_cast<const uint4*>(src + (size_t)idx * 8);
        int e0 = idx * 8;
        float* dst = &L[(e0 >> 6) * 68 + (e0 & 63)];
        float4 a, b;
        a.x = b2f((unsigned short)(v.x & 0xffff));
        a.y = b2f((unsigned short)(v.x >> 16));
        a.z = b2f((unsigned short)(v.y & 0xffff));
        a.w = b2f((unsigned short)(v.y >> 16));
        b.x = b2f((unsigned short)(v.z & 0xffff));
        b.y = b2f((unsigned short)(v.z >> 16));
        b.z = b2f((unsigned short)(v.w & 0xffff));
        b.w = b2f((unsigned short)(v.w >> 16));
        *(float4*)dst = a;
        *(float4*)(dst + 4) = b;
    }
    __syncthreads();

    const int q0 = lane & 15;
    const int g  = lane >> 4;

    float e[4] = {0.f, 0.f, 0.f, 0.f};
    const float* Qr = &L[q0 * 68];
    const float* K0 = &L[(16 + g * 4) * 68];
#pragma unroll
    for (int d = 0; d < 64; d += 4) {
        float4 q4 = *(const float4*)(Qr + d);
#pragma unroll
        for (int j = 0; j < 4; ++j) {
            float4 k4 = *(const float4*)(K0 + j * 68 + d);
            e[j] += q4.x * k4.x + q4.y * k4.y + q4.z * k4.z + q4.w * k4.w;
        }
    }
#pragma unroll
    for (int j = 0; j < 4; ++j) e[j] *= 0.125f;

    float m = fmaxf(fmaxf(e[0], e[1]), fmaxf(e[2], e[3]));
    m = fmaxf(m, __shfl_xor(m, 16));
    m = fmaxf(m, __shfl_xor(m, 32));
    float p[4], sum = 0.f;
#pragma unroll
    for (int j = 0; j < 4; ++j) { p[j] = __expf(e[j] - m); sum += p[j]; }
    sum += __shfl_xor(sum, 16);
    sum += __shfl_xor(sum, 32);
    const float inv = 1.0f / sum;

    float prow[16];
#pragma unroll
    for (int j = 0; j < 4; ++j) {
        prow[g * 4 + j]         = p[j] * inv;
        prow[((g ^ 1) * 4) + j] = __shfl_xor(p[j], 16) * inv;
        prow[((g ^ 2) * 4) + j] = __shfl_xor(p[j], 32) * inv;
        prow[((g ^ 3) * 4) + j] = __shfl_xor(p[j], 48) * inv;
    }

    const int d0 = g * 16;
    float4 o4[4] = {};
#pragma unroll
    for (int k = 0; k < 16; ++k) {
        const float p1 = prow[k];
        const float* Vr = &L[(32 + k) * 68 + d0];
#pragma unroll
        for (int c = 0; c < 4; ++c) {
            float4 v = *(const float4*)(Vr + c * 4);
            o4[c].x += p1 * v.x; o4[c].y += p1 * v.y;
            o4[c].z += p1 * v.z; o4[c].w += p1 * v.w;
        }
    }
    unsigned short outv[16];
#pragma unroll
    for (int c = 0; c < 4; ++c) {
        outv[c * 4 + 0] = f2b(o4[c].x); outv[c * 4 + 1] = f2b(o4[c].y);
        outv[c * 4 + 2] = f2b(o4[c].z); outv[c * 4 + 3] = f2b(o4[c].w);
    }
    const int sp = q0 * 128 + (s >> 4);
    size_t off = ((size_t)n * 2048 + sp) * 1024 + (size_t)(s & 15) * 64 + d0;
    uint4* dst = reinterpret_cast<uint4*>(T + off);
    const uint4* sv = reinterpret_cast<const uint4*>(outv);
    dst[0] = sv[0];
    dst[1] = sv[1];
}

extern "C" void kernel_launch(void* const* d_in, const int* in_sizes, int n_in,
                              void* d_out, int out_size, void* d_ws, size_t ws_size,
                              hipStream_t stream) {
    const float* x     = (const float*)d_in[0];   // (4,2048,1024)
    const float* w_qkv = (const float*)d_in[1];   // (3072,1024)
    const float* b_qkv = (const float*)d_in[2];   // (3072,)
    const float* w_out = (const float*)d_in[3];   // (1024,1024)
    const float* b_out = (const float*)d_in[4];   // (1024,)
    float* out = (float*)d_out;                   // (4,2048,1024) fp32

    const int M = 8192, E = 3072, K = 1024, D = 1024;

    // ws: [0, 50.33M) qkv bf16 -> later W2b; [50.33M, 67.11M) T bf16.
    // d_out doubles as scratch until GEMM2 rewrites it: W1b then X16.
    bf16* qkv = (bf16*)d_ws;
    bf16* T   = qkv + (size_t)M * E;
    bf16* W2b = qkv;
    bf16* W1b = (bf16*)d_out;
    bf16* X16 = W1b + (size_t)E * K;

    dim3 blk(256);

    // 1) x fp32 -> bf16 (d_out scratch)
    cvt_f32_bf16<<<dim3(M * K / 4 / 256), blk, 0, stream>>>(x, X16, M * K / 4);
    // 2) w_qkv fp32 -> bf16 (d_out scratch)
    cvt_f32_bf16<<<dim3(E * K / 4 / 256), blk, 0, stream>>>(w_qkv, W1b, E * K / 4);
    // 3) QKV projection: 8-phase 256^2, grid 12x32=384 (%8==0) -> bf16 qkv
    gemm8p<bf16><<<dim3((E / 256) * (M / 256)), dim3(512), 0, stream>>>(
        X16, W1b, b_qkv, qkv, M, E, K, E / 256);
    // 4) per-token heads-axis attention + scrambled reshape -> bf16 T
    attn_kernel<<<dim3(M / 4), blk, 0, stream>>>(qkv, T);
    // 5) w_out fp32 -> bf16 (dead qkv region)
    cvt_f32_bf16<<<dim3(D * K / 4 / 256), blk, 0, stream>>>(w_out, W2b, D * K / 4);
    // 6) output projection: 8-phase 256^2, grid 4x32=128 (%8==0) -> fp32
    gemm8p<float><<<dim3((D / 256) * (M / 256)), dim3(512), 0, stream>>>(
        T, W2b, b_out, out, M, D, K, D / 256);
}

// Round 8
// 130.054 us; speedup vs baseline: 1.4203x; 1.0591x over previous
//
#include <hip/hip_runtime.h>
#include <hip/hip_bf16.h>

// N=4, S=2048, D_MODEL=1024, HEADS=16, HEAD_DIM=64. M = 8192 tokens, E = 3072.

typedef __hip_bfloat16 bf16;
using bf16x8 = __attribute__((ext_vector_type(8))) short;
using f32x4  = __attribute__((ext_vector_type(4))) float;

__device__ __forceinline__ float b2f(unsigned short u) {
    return __uint_as_float(((unsigned)u) << 16);
}
__device__ __forceinline__ unsigned short f2b(float f) {
    bf16 h = __float2bfloat16(f);
    return *reinterpret_cast<unsigned short*>(&h);
}
__device__ __forceinline__ void store1(float* p, float v) { *p = v; }
__device__ __forceinline__ void store1(bf16* p, float v) { *p = __float2bfloat16(v); }

// async global->LDS, 16B per lane. LDS dest = wave-uniform base + lane*16.
__device__ __forceinline__ void gload_lds16(const bf16* g, bf16* l) {
    __builtin_amdgcn_global_load_lds(
        (const __attribute__((address_space(1))) void*)g,
        (__attribute__((address_space(3))) void*)l, 16, 0, 0);
}

#define BAR()  __builtin_amdgcn_s_barrier()
#define LGK()  asm volatile("s_waitcnt lgkmcnt(0)" ::: "memory")
#define VMC(N) asm volatile("s_waitcnt vmcnt(" #N ")" ::: "memory")

// ============================================================================
// Fill-exact pipelined GEMM. C[M][N] = A[M][K]*B[N][K]^T + bias. K mult of 64.
// Tile 128(M) x 256(N), BK=64. 512 thr = 8 waves (2Mx4N), wave out 64x64 =
// acc[4][4]. LDS 144KB = 3 bufs x (A 128x64 + B 256x64) bf16 -> 1 block/CU.
// Grids: GEMM1 768 = 3.0 exact CU rounds; GEMM2 256 = 1.0 round (100% fill).
// Swizzle (verified r7, 0 conflicts): read byte ^= (row&7)<<4; inverse on
// GLOBAL source k: kel = ((lane&7)^(lane>>3))*8; linear gload_lds dest.
// Schedule: per K-tile 2 phases {ds_read 8 frags; stage; BAR; lgkmcnt(0);
// setprio(1); 16 MFMA; setprio(0); BAR}. Stage rotation: ph1 stages (t+2).A,
// ph2 stages (t+2).B0,B1 into buf (t+2)%3 — read-dead since iter t-1, and
// (t+2)%3 differs from live bufs t%3,(t+1)%3. vmcnt(6) at ph2: 6 younger
// (t+2) outstanding => oldest 6 (t+1) forced complete before next iter.
// Last two tiles: stages guarded off => VMC(0) to cover t_{nt-1}.
// ============================================================================
template <typename CT>
__global__ __launch_bounds__(512, 2)
void gemm3b(const bf16* __restrict__ A, const bf16* __restrict__ B,
            const float* __restrict__ bias, CT* __restrict__ C,
            int M, int N, int K, int gx) {
    __shared__ alignas(1024) bf16 smem[3][384 * 64];  // per buf: A[0:8192) B[8192:24576)

    const int t    = threadIdx.x;
    const int lane = t & 63;
    const int wid  = t >> 6;
    const int wr   = wid >> 2;   // 0..1  (M half)
    const int wc   = wid & 3;    // 0..3  (N quarter)

    // XCD-aware bijective remap (gridDim.x % 8 == 0)
    const int nwg = gridDim.x;
    const int bid = blockIdx.x;
    const int wg  = (bid & 7) * (nwg >> 3) + (bid >> 3);
    const int m0  = (wg / gx) * 128;
    const int n0  = (wg % gx) * 256;

    const int nt = K / 64;

    // staging coords (inverse swizzle on global k)
    const int srow = lane >> 3;                        // 0..7
    const int kel  = ((lane & 7) ^ (lane >> 3)) * 8;   // pre-swizzled k elems

    auto stageA = [&](int tt) {                        // 128x64, 1 call, 2 gload/wave
        if (tt >= nt) return;
        bf16* lp = &smem[tt % 3][wid * 1024];
        const bf16* gp = A + (size_t)(m0 + wid * 16 + srow) * K + tt * 64 + kel;
        gload_lds16(gp, lp);
        gload_lds16(gp + (size_t)8 * K, lp + 512);
    };
    auto stageB = [&](int tt, int h) {                 // 128 rows per call
        if (tt >= nt) return;
        bf16* lp = &smem[tt % 3][8192 + h * 8192 + wid * 1024];
        const bf16* gp = B + (size_t)(n0 + h * 128 + wid * 16 + srow) * K + tt * 64 + kel;
        gload_lds16(gp, lp);
        gload_lds16(gp + (size_t)8 * K, lp + 512);
    };

    // swizzled ds_read of one 16x16x32 fragment
    const int arow_base = wr * 64 + (lane & 15);
    const int brow_base = wc * 64 + (lane & 15);
    const int kqb       = (lane >> 4) * 16;            // k byte sub-offset
    auto LDA = [&](int buf, int kk, int m) -> bf16x8 {
        const int row = arow_base + m * 16;
        const int ab  = row * 128 + ((kk * 64 + kqb) ^ ((row & 7) << 4));
        return *(const bf16x8*)((const char*)&smem[buf][0] + ab);
    };
    auto LDB = [&](int buf, int kk, int n) -> bf16x8 {
        const int row = brow_base + n * 16;
        const int bb  = 16384 + row * 128 + ((kk * 64 + kqb) ^ ((row & 7) << 4));
        return *(const bf16x8*)((const char*)&smem[buf][0] + bb);
    };

    f32x4 acc[4][4] = {};
    bf16x8 af[4], bfr[4];

    // prologue: stage t0, t1 (12 loads); VMC(6) => t0 landed
    stageA(0); stageB(0, 0); stageB(0, 1);
    stageA(1); stageB(1, 0); stageB(1, 1);
    VMC(6);
    BAR();

    for (int tt = 0; tt < nt; ++tt) {
        const int buf = tt % 3;

        // ph1: read kk0 frags; stage (tt+2).A
#pragma unroll
        for (int m = 0; m < 4; ++m) af[m] = LDA(buf, 0, m);
#pragma unroll
        for (int n = 0; n < 4; ++n) bfr[n] = LDB(buf, 0, n);
        stageA(tt + 2);
        BAR(); LGK();
        __builtin_amdgcn_s_setprio(1);
#pragma unroll
        for (int m = 0; m < 4; ++m)
#pragma unroll
            for (int n = 0; n < 4; ++n)
                acc[m][n] = __builtin_amdgcn_mfma_f32_16x16x32_bf16(
                    af[m], bfr[n], acc[m][n], 0, 0, 0);
        __builtin_amdgcn_s_setprio(0);
        BAR();

        // ph2: read kk1 frags; stage (tt+2).B; counted wait
#pragma unroll
        for (int m = 0; m < 4; ++m) af[m] = LDA(buf, 1, m);
#pragma unroll
        for (int n = 0; n < 4; ++n) bfr[n] = LDB(buf, 1, n);
        stageB(tt + 2, 0); stageB(tt + 2, 1);
        if (tt < nt - 2) { VMC(6); } else { VMC(0); }
        BAR(); LGK();
        __builtin_amdgcn_s_setprio(1);
#pragma unroll
        for (int m = 0; m < 4; ++m)
#pragma unroll
            for (int n = 0; n < 4; ++n)
                acc[m][n] = __builtin_amdgcn_mfma_f32_16x16x32_bf16(
                    af[m], bfr[n], acc[m][n], 0, 0, 0);
        __builtin_amdgcn_s_setprio(0);
        BAR();
    }

    // epilogue
#pragma unroll
    for (int m = 0; m < 4; ++m) {
        const int row = m0 + wr * 64 + m * 16 + (lane >> 4) * 4;
#pragma unroll
        for (int n = 0; n < 4; ++n) {
            const int col = n0 + wc * 64 + n * 16 + (lane & 15);
            const float bval = bias[col];
#pragma unroll
            for (int r = 0; r < 4; ++r)
                store1(&C[(size_t)(row + r) * N + col], acc[m][n][r] + bval);
        }
    }
}

// ---- fp32 -> bf16 conversion, 4 elems/thread ----
__global__ __launch_bounds__(256)
void cvt_f32_bf16(const float* __restrict__ in, bf16* __restrict__ out, int n4) {
    int i = blockIdx.x * 256 + threadIdx.x;
    if (i >= n4) return;
    float4 v = ((const float4*)in)[i];
    ushort4 o = {f2b(v.x), f2b(v.y), f2b(v.z), f2b(v.w)};
    ((ushort4*)out)[i] = o;
}

// ---- Per-token attention over heads axis + scrambled T write ----
// stride 68 floats (16B-aligned rows, <=2-way banks), float4 everywhere.
__global__ __launch_bounds__(256)
void attn_kernel(const bf16* __restrict__ qkv, bf16* __restrict__ T) {
    __shared__ float lds[4][48 * 68];

    const int wave = threadIdx.x >> 6;
    const int lane = threadIdx.x & 63;
    const int token = blockIdx.x * 4 + wave;
    const int n = token >> 11;
    const int s = token & 2047;

    float* L = lds[wave];
    const bf16* src = qkv + (size_t)token * 3072;

#pragma unroll
    for (int i = 0; i < 6; ++i) {
        int idx = i * 64 + lane;
        uint4 v = *reinterpret_cast<const uint4*>(src + (size_t)idx * 8);
        int e0 = idx * 8;
        float* dst = &L[(e0 >> 6) * 68 + (e0 & 63)];
        float4 a, b;
        a.x = b2f((unsigned short)(v.x & 0xffff));
        a.y = b2f((unsigned short)(v.x >> 16));
        a.z = b2f((unsigned short)(v.y & 0xffff));
        a.w = b2f((unsigned short)(v.y >> 16));
        b.x = b2f((unsigned short)(v.z & 0xffff));
        b.y = b2f((unsigned short)(v.z >> 16));
        b.z = b2f((unsigned short)(v.w & 0xffff));
        b.w = b2f((unsigned short)(v.w >> 16));
        *(float4*)dst = a;
        *(float4*)(dst + 4) = b;
    }
    __syncthreads();

    const int q0 = lane & 15;
    const int g  = lane >> 4;

    float e[4] = {0.f, 0.f, 0.f, 0.f};
    const float* Qr = &L[q0 * 68];
    const float* K0 = &L[(16 + g * 4) * 68];
#pragma unroll
    for (int d = 0; d < 64; d += 4) {
        float4 q4 = *(const float4*)(Qr + d);
#pragma unroll
        for (int j = 0; j < 4; ++j) {
            float4 k4 = *(const float4*)(K0 + j * 68 + d);
            e[j] += q4.x * k4.x + q4.y * k4.y + q4.z * k4.z + q4.w * k4.w;
        }
    }
#pragma unroll
    for (int j = 0; j < 4; ++j) e[j] *= 0.125f;

    float m = fmaxf(fmaxf(e[0], e[1]), fmaxf(e[2], e[3]));
    m = fmaxf(m, __shfl_xor(m, 16));
    m = fmaxf(m, __shfl_xor(m, 32));
    float p[4], sum = 0.f;
#pragma unroll
    for (int j = 0; j < 4; ++j) { p[j] = __expf(e[j] - m); sum += p[j]; }
    sum += __shfl_xor(sum, 16);
    sum += __shfl_xor(sum, 32);
    const float inv = 1.0f / sum;

    float prow[16];
#pragma unroll
    for (int j = 0; j < 4; ++j) {
        prow[g * 4 + j]         = p[j] * inv;
        prow[((g ^ 1) * 4) + j] = __shfl_xor(p[j], 16) * inv;
        prow[((g ^ 2) * 4) + j] = __shfl_xor(p[j], 32) * inv;
        prow[((g ^ 3) * 4) + j] = __shfl_xor(p[j], 48) * inv;
    }

    const int d0 = g * 16;
    float4 o4[4] = {};
#pragma unroll
    for (int k = 0; k < 16; ++k) {
        const float p1 = prow[k];
        const float* Vr = &L[(32 + k) * 68 + d0];
#pragma unroll
        for (int c = 0; c < 4; ++c) {
            float4 v = *(const float4*)(Vr + c * 4);
            o4[c].x += p1 * v.x; o4[c].y += p1 * v.y;
            o4[c].z += p1 * v.z; o4[c].w += p1 * v.w;
        }
    }
    unsigned short outv[16];
#pragma unroll
    for (int c = 0; c < 4; ++c) {
        outv[c * 4 + 0] = f2b(o4[c].x); outv[c * 4 + 1] = f2b(o4[c].y);
        outv[c * 4 + 2] = f2b(o4[c].z); outv[c * 4 + 3] = f2b(o4[c].w);
    }
    const int sp = q0 * 128 + (s >> 4);
    size_t off = ((size_t)n * 2048 + sp) * 1024 + (size_t)(s & 15) * 64 + d0;
    uint4* dst = reinterpret_cast<uint4*>(T + off);
    const uint4* sv = reinterpret_cast<const uint4*>(outv);
    dst[0] = sv[0];
    dst[1] = sv[1];
}

extern "C" void kernel_launch(void* const* d_in, const int* in_sizes, int n_in,
                              void* d_out, int out_size, void* d_ws, size_t ws_size,
                              hipStream_t stream) {
    const float* x     = (const float*)d_in[0];   // (4,2048,1024)
    const float* w_qkv = (const float*)d_in[1];   // (3072,1024)
    const float* b_qkv = (const float*)d_in[2];   // (3072,)
    const float* w_out = (const float*)d_in[3];   // (1024,1024)
    const float* b_out = (const float*)d_in[4];   // (1024,)
    float* out = (float*)d_out;                   // (4,2048,1024) fp32

    const int M = 8192, E = 3072, K = 1024, D = 1024;

    // ws: [0, 50.33M) qkv bf16 -> later W2b; [50.33M, 67.11M) T bf16.
    // d_out doubles as scratch until GEMM2 rewrites it: W1b then X16.
    bf16* qkv = (bf16*)d_ws;
    bf16* T   = qkv + (size_t)M * E;
    bf16* W2b = qkv;
    bf16* W1b = (bf16*)d_out;
    bf16* X16 = W1b + (size_t)E * K;

    dim3 blk(256);

    // 1) x fp32 -> bf16 (d_out scratch)
    cvt_f32_bf16<<<dim3(M * K / 4 / 256), blk, 0, stream>>>(x, X16, M * K / 4);
    // 2) w_qkv fp32 -> bf16 (d_out scratch)
    cvt_f32_bf16<<<dim3(E * K / 4 / 256), blk, 0, stream>>>(w_qkv, W1b, E * K / 4);
    // 3) QKV projection: 128x256 tiles, grid 64*12=768 = 3.0 CU rounds
    gemm3b<bf16><<<dim3((M / 128) * (E / 256)), dim3(512), 0, stream>>>(
        X16, W1b, b_qkv, qkv, M, E, K, E / 256);
    // 4) per-token heads-axis attention + scrambled reshape -> bf16 T
    attn_kernel<<<dim3(M / 4), blk, 0, stream>>>(qkv, T);
    // 5) w_out fp32 -> bf16 (dead qkv region)
    cvt_f32_bf16<<<dim3(D * K / 4 / 256), blk, 0, stream>>>(w_out, W2b, D * K / 4);
    // 6) output projection: 128x256 tiles, grid 64*4=256 = 1.0 CU round
    gemm3b<float><<<dim3((M / 128) * (D / 256)), dim3(512), 0, stream>>>(
        T, W2b, b_out, out, M, D, K, D / 256);
}

// Round 9
// 127.940 us; speedup vs baseline: 1.4437x; 1.0165x over previous
//
#include <hip/hip_runtime.h>
#include <hip/hip_bf16.h>

// N=4, S=2048, D_MODEL=1024, HEADS=16, HEAD_DIM=64. M = 8192 tokens, E = 3072.

typedef __hip_bfloat16 bf16;
using bf16x8 = __attribute__((ext_vector_type(8))) short;
using f32x4  = __attribute__((ext_vector_type(4))) float;

__device__ __forceinline__ float b2f(unsigned short u) {
    return __uint_as_float(((unsigned)u) << 16);
}
__device__ __forceinline__ unsigned short f2b(float f) {
    bf16 h = __float2bfloat16(f);
    return *reinterpret_cast<unsigned short*>(&h);
}
__device__ __forceinline__ void store1(float* p, float v) { *p = v; }
__device__ __forceinline__ void store1(bf16* p, float v) { *p = __float2bfloat16(v); }

// async global->LDS, 16B per lane. LDS dest = wave-uniform base + lane*16.
__device__ __forceinline__ void gload_lds16(const bf16* g, bf16* l) {
    __builtin_amdgcn_global_load_lds(
        (const __attribute__((address_space(1))) void*)g,
        (__attribute__((address_space(3))) void*)l, 16, 0, 0);
}

#define BAR()   __builtin_amdgcn_s_barrier()
#define LGKM(N) asm volatile("s_waitcnt lgkmcnt(" #N ")" ::: "memory")
#define VMC(N)  asm volatile("s_waitcnt vmcnt(" #N ")" ::: "memory")

// ============================================================================
// Pipelined GEMM, overlap LDS-reads with MFMA. C = A*B^T + bias. K mult of 64.
// Tile 128(M) x 256(N), BK=64. 512 thr = 8 waves (2Mx4N), wave out 64x64 =
// acc[4][4]. LDS 144KB = 3 bufs x (A 128x64 + B 256x64) -> 1 block/CU.
// Grids fill-exact: GEMM1 768 = 3.0 CU rounds; GEMM2 256 = 1.0 round.
// Swizzle (verified r7/r8, 0 conflicts): read byte ^= (row&7)<<4; inverse on
// GLOBAL source k (kel = ((lane&7)^(lane>>3))*8); linear gload_lds dest.
// Per-tile schedule (reg frags double-buffered cur=kk0 / alt=kk1):
//   A: issue kk1 ds_reads -> alt          (8 reads fly)
//   B: stage t+2 (6 gloads)
//   C: lgkmcnt(8)  [cur ready, alt flying]; MFMA kk0 overlaps alt reads
//   D: vmcnt(6)+BAR  [t+1 landed+visible; tails: vmcnt(0)]
//   E: issue (t+1,kk0) ds_reads -> cur    (8 reads fly)
//   F: lgkmcnt(8)  [alt ready, cur flying]; MFMA kk1 overlaps cur reads
//   G: BAR  [all frag reads of tile t done (per C/F) before t+3 stage]
// vmcnt: 6 issues/tile; at D queue=[t+1:6, t+2:6] -> VMC(6) completes t+1.
// Hazards: stage(t+2) at B overwrites buf (t-1)%3 whose last reads completed
// before G of t-1 (lgkm proofs) -> BAR(G) orders them. lgkm counts are
// redundant with compiler dataflow waits; only vmcnt chain is load-bearing.
// ============================================================================
template <typename CT>
__global__ __launch_bounds__(512, 2)
void gemm3p(const bf16* __restrict__ A, const bf16* __restrict__ B,
            const float* __restrict__ bias, CT* __restrict__ C,
            int M, int N, int K, int gx) {
    __shared__ alignas(1024) bf16 smem[3][384 * 64];  // per buf: A[0:8192) B[8192:24576)

    const int t    = threadIdx.x;
    const int lane = t & 63;
    const int wid  = t >> 6;
    const int wr   = wid >> 2;   // 0..1  (M half)
    const int wc   = wid & 3;    // 0..3  (N quarter)

    // XCD-aware bijective remap (gridDim.x % 8 == 0)
    const int nwg = gridDim.x;
    const int bid = blockIdx.x;
    const int wg  = (bid & 7) * (nwg >> 3) + (bid >> 3);
    const int m0  = (wg / gx) * 128;
    const int n0  = (wg % gx) * 256;

    const int nt = K / 64;

    // staging coords (inverse swizzle on global k)
    const int srow = lane >> 3;                        // 0..7
    const int kel  = ((lane & 7) ^ (lane >> 3)) * 8;   // pre-swizzled k elems

    auto stageA = [&](int tt) {
        if (tt >= nt) return;
        bf16* lp = &smem[tt % 3][wid * 1024];
        const bf16* gp = A + (size_t)(m0 + wid * 16 + srow) * K + tt * 64 + kel;
        gload_lds16(gp, lp);
        gload_lds16(gp + (size_t)8 * K, lp + 512);
    };
    auto stageB = [&](int tt, int h) {
        if (tt >= nt) return;
        bf16* lp = &smem[tt % 3][8192 + h * 8192 + wid * 1024];
        const bf16* gp = B + (size_t)(n0 + h * 128 + wid * 16 + srow) * K + tt * 64 + kel;
        gload_lds16(gp, lp);
        gload_lds16(gp + (size_t)8 * K, lp + 512);
    };

    // swizzled ds_read of one 16x16x32 fragment (16B aligned)
    const int arow_base = wr * 64 + (lane & 15);
    const int brow_base = wc * 64 + (lane & 15);
    const int kqb       = (lane >> 4) * 16;            // k byte sub-offset
    auto LDA = [&](int buf, int kk, int m) -> bf16x8 {
        const int row = arow_base + m * 16;
        const int ab  = row * 128 + ((kk * 64 + kqb) ^ ((row & 7) << 4));
        return *(const bf16x8*)((const char*)&smem[buf][0] + ab);
    };
    auto LDB = [&](int buf, int kk, int n) -> bf16x8 {
        const int row = brow_base + n * 16;
        const int bb  = 16384 + row * 128 + ((kk * 64 + kqb) ^ ((row & 7) << 4));
        return *(const bf16x8*)((const char*)&smem[buf][0] + bb);
    };

    f32x4 acc[4][4] = {};
    bf16x8 afc[4], bfc[4];   // cur: kk0 frags
    bf16x8 afa[4], bfa[4];   // alt: kk1 frags

    // prologue: stage t0,t1 (12 gloads); t0 landed; prime cur with (t0,kk0)
    stageA(0); stageB(0, 0); stageB(0, 1);
    stageA(1); stageB(1, 0); stageB(1, 1);
    VMC(6);
    BAR();
#pragma unroll
    for (int m = 0; m < 4; ++m) afc[m] = LDA(0, 0, m);
#pragma unroll
    for (int n = 0; n < 4; ++n) bfc[n] = LDB(0, 0, n);

    for (int tt = 0; tt < nt; ++tt) {
        const int buf = tt % 3;

        // A: issue kk1 reads -> alt
#pragma unroll
        for (int m = 0; m < 4; ++m) afa[m] = LDA(buf, 1, m);
#pragma unroll
        for (int n = 0; n < 4; ++n) bfa[n] = LDB(buf, 1, n);
        // B: stage t+2
        stageA(tt + 2); stageB(tt + 2, 0); stageB(tt + 2, 1);
        // C: cur ready (8 alt reads still flying); MFMA kk0
        LGKM(8);
        __builtin_amdgcn_s_setprio(1);
#pragma unroll
        for (int m = 0; m < 4; ++m)
#pragma unroll
            for (int n = 0; n < 4; ++n)
                acc[m][n] = __builtin_amdgcn_mfma_f32_16x16x32_bf16(
                    afc[m], bfc[n], acc[m][n], 0, 0, 0);
        __builtin_amdgcn_s_setprio(0);
        // D: t+1 landed + visible
        if (tt < nt - 2) { VMC(6); } else { VMC(0); }
        BAR();
        // E: issue next-tile kk0 reads -> cur
        if (tt + 1 < nt) {
            const int nb = (tt + 1) % 3;
#pragma unroll
            for (int m = 0; m < 4; ++m) afc[m] = LDA(nb, 0, m);
#pragma unroll
            for (int n = 0; n < 4; ++n) bfc[n] = LDB(nb, 0, n);
            // F: alt ready (8 cur reads flying); MFMA kk1
            LGKM(8);
        } else {
            LGKM(0);
        }
        __builtin_amdgcn_s_setprio(1);
#pragma unroll
        for (int m = 0; m < 4; ++m)
#pragma unroll
            for (int n = 0; n < 4; ++n)
                acc[m][n] = __builtin_amdgcn_mfma_f32_16x16x32_bf16(
                    afa[m], bfa[n], acc[m][n], 0, 0, 0);
        __builtin_amdgcn_s_setprio(0);
        // G: all tile-t frag reads done before next tile's stage overwrites
        BAR();
    }

    // epilogue
#pragma unroll
    for (int m = 0; m < 4; ++m) {
        const int row = m0 + wr * 64 + m * 16 + (lane >> 4) * 4;
#pragma unroll
        for (int n = 0; n < 4; ++n) {
            const int col = n0 + wc * 64 + n * 16 + (lane & 15);
            const float bval = bias[col];
#pragma unroll
            for (int r = 0; r < 4; ++r)
                store1(&C[(size_t)(row + r) * N + col], acc[m][n][r] + bval);
        }
    }
}

// ---- fp32 -> bf16 conversion, 4 elems/thread ----
__global__ __launch_bounds__(256)
void cvt_f32_bf16(const float* __restrict__ in, bf16* __restrict__ out, int n4) {
    int i = blockIdx.x * 256 + threadIdx.x;
    if (i >= n4) return;
    float4 v = ((const float4*)in)[i];
    ushort4 o = {f2b(v.x), f2b(v.y), f2b(v.z), f2b(v.w)};
    ((ushort4*)out)[i] = o;
}

// ---- Per-token attention over heads axis + scrambled T write ----
// stride 68 floats (16B-aligned rows, <=2-way banks), float4 everywhere.
__global__ __launch_bounds__(256)
void attn_kernel(const bf16* __restrict__ qkv, bf16* __restrict__ T) {
    __shared__ float lds[4][48 * 68];

    const int wave = threadIdx.x >> 6;
    const int lane = threadIdx.x & 63;
    const int token = blockIdx.x * 4 + wave;
    const int n = token >> 11;
    const int s = token & 2047;

    float* L = lds[wave];
    const bf16* src = qkv + (size_t)token * 3072;

#pragma unroll
    for (int i = 0; i < 6; ++i) {
        int idx = i * 64 + lane;
        uint4 v = *reinterpret_cast<const uint4*>(src + (size_t)idx * 8);
        int e0 = idx * 8;
        float* dst = &L[(e0 >> 6) * 68 + (e0 & 63)];
        float4 a, b;
        a.x = b2f((unsigned short)(v.x & 0xffff));
        a.y = b2f((unsigned short)(v.x >> 16));
        a.z = b2f((unsigned short)(v.y & 0xffff));
        a.w = b2f((unsigned short)(v.y >> 16));
        b.x = b2f((unsigned short)(v.z & 0xffff));
        b.y = b2f((unsigned short)(v.z >> 16));
        b.z = b2f((unsigned short)(v.w & 0xffff));
        b.w = b2f((unsigned short)(v.w >> 16));
        *(float4*)dst = a;
        *(float4*)(dst + 4) = b;
    }
    __syncthreads();

    const int q0 = lane & 15;
    const int g  = lane >> 4;

    float e[4] = {0.f, 0.f, 0.f, 0.f};
    const float* Qr = &L[q0 * 68];
    const float* K0 = &L[(16 + g * 4) * 68];
#pragma unroll
    for (int d = 0; d < 64; d += 4) {
        float4 q4 = *(const float4*)(Qr + d);
#pragma unroll
        for (int j = 0; j < 4; ++j) {
            float4 k4 = *(const float4*)(K0 + j * 68 + d);
            e[j] += q4.x * k4.x + q4.y * k4.y + q4.z * k4.z + q4.w * k4.w;
        }
    }
#pragma unroll
    for (int j = 0; j < 4; ++j) e[j] *= 0.125f;

    float m = fmaxf(fmaxf(e[0], e[1]), fmaxf(e[2], e[3]));
    m = fmaxf(m, __shfl_xor(m, 16));
    m = fmaxf(m, __shfl_xor(m, 32));
    float p[4], sum = 0.f;
#pragma unroll
    for (int j = 0; j < 4; ++j) { p[j] = __expf(e[j] - m); sum += p[j]; }
    sum += __shfl_xor(sum, 16);
    sum += __shfl_xor(sum, 32);
    const float inv = 1.0f / sum;

    float prow[16];
#pragma unroll
    for (int j = 0; j < 4; ++j) {
        prow[g * 4 + j]         = p[j] * inv;
        prow[((g ^ 1) * 4) + j] = __shfl_xor(p[j], 16) * inv;
        prow[((g ^ 2) * 4) + j] = __shfl_xor(p[j], 32) * inv;
        prow[((g ^ 3) * 4) + j] = __shfl_xor(p[j], 48) * inv;
    }

    const int d0 = g * 16;
    float4 o4[4] = {};
#pragma unroll
    for (int k = 0; k < 16; ++k) {
        const float p1 = prow[k];
        const float* Vr = &L[(32 + k) * 68 + d0];
#pragma unroll
        for (int c = 0; c < 4; ++c) {
            float4 v = *(const float4*)(Vr + c * 4);
            o4[c].x += p1 * v.x; o4[c].y += p1 * v.y;
            o4[c].z += p1 * v.z; o4[c].w += p1 * v.w;
        }
    }
    unsigned short outv[16];
#pragma unroll
    for (int c = 0; c < 4; ++c) {
        outv[c * 4 + 0] = f2b(o4[c].x); outv[c * 4 + 1] = f2b(o4[c].y);
        outv[c * 4 + 2] = f2b(o4[c].z); outv[c * 4 + 3] = f2b(o4[c].w);
    }
    const int sp = q0 * 128 + (s >> 4);
    size_t off = ((size_t)n * 2048 + sp) * 1024 + (size_t)(s & 15) * 64 + d0;
    uint4* dst = reinterpret_cast<uint4*>(T + off);
    const uint4* sv = reinterpret_cast<const uint4*>(outv);
    dst[0] = sv[0];
    dst[1] = sv[1];
}

extern "C" void kernel_launch(void* const* d_in, const int* in_sizes, int n_in,
                              void* d_out, int out_size, void* d_ws, size_t ws_size,
                              hipStream_t stream) {
    const float* x     = (const float*)d_in[0];   // (4,2048,1024)
    const float* w_qkv = (const float*)d_in[1];   // (3072,1024)
    const float* b_qkv = (const float*)d_in[2];   // (3072,)
    const float* w_out = (const float*)d_in[3];   // (1024,1024)
    const float* b_out = (const float*)d_in[4];   // (1024,)
    float* out = (float*)d_out;                   // (4,2048,1024) fp32

    const int M = 8192, E = 3072, K = 1024, D = 1024;

    // ws: [0, 50.33M) qkv bf16 -> later W2b; [50.33M, 67.11M) T bf16.
    // d_out doubles as scratch until GEMM2 rewrites it: W1b then X16.
    bf16* qkv = (bf16*)d_ws;
    bf16* T   = qkv + (size_t)M * E;
    bf16* W2b = qkv;
    bf16* W1b = (bf16*)d_out;
    bf16* X16 = W1b + (size_t)E * K;

    dim3 blk(256);

    // 1) x fp32 -> bf16 (d_out scratch)
    cvt_f32_bf16<<<dim3(M * K / 4 / 256), blk, 0, stream>>>(x, X16, M * K / 4);
    // 2) w_qkv fp32 -> bf16 (d_out scratch)
    cvt_f32_bf16<<<dim3(E * K / 4 / 256), blk, 0, stream>>>(w_qkv, W1b, E * K / 4);
    // 3) QKV projection: 128x256 tiles, grid 64*12=768 = 3.0 CU rounds
    gemm3p<bf16><<<dim3((M / 128) * (E / 256)), dim3(512), 0, stream>>>(
        X16, W1b, b_qkv, qkv, M, E, K, E / 256);
    // 4) per-token heads-axis attention + scrambled reshape -> bf16 T
    attn_kernel<<<dim3(M / 4), blk, 0, stream>>>(qkv, T);
    // 5) w_out fp32 -> bf16 (dead qkv region)
    cvt_f32_bf16<<<dim3(D * K / 4 / 256), blk, 0, stream>>>(w_out, W2b, D * K / 4);
    // 6) output projection: 128x256 tiles, grid 64*4=256 = 1.0 CU round
    gemm3p<float><<<dim3((M / 128) * (D / 256)), dim3(512), 0, stream>>>(
        T, W2b, b_out, out, M, D, K, D / 256);
}

// Round 10
// 124.098 us; speedup vs baseline: 1.4884x; 1.0310x over previous
//
#include <hip/hip_runtime.h>
#include <hip/hip_bf16.h>

// N=4, S=2048, D_MODEL=1024, HEADS=16, HEAD_DIM=64. M = 8192 tokens, E = 3072.

typedef __hip_bfloat16 bf16;
using bf16x8 = __attribute__((ext_vector_type(8))) short;
using f32x4  = __attribute__((ext_vector_type(4))) float;

__device__ __forceinline__ float b2f(unsigned short u) {
    return __uint_as_float(((unsigned)u) << 16);
}
__device__ __forceinline__ unsigned short f2b(float f) {
    bf16 h = __float2bfloat16(f);
    return *reinterpret_cast<unsigned short*>(&h);
}
__device__ __forceinline__ void store1(float* p, float v) { *p = v; }
__device__ __forceinline__ void store1(bf16* p, float v) { *p = __float2bfloat16(v); }

// async global->LDS, 16B per lane. LDS dest = wave-uniform base + lane*16.
__device__ __forceinline__ void gload_lds16(const bf16* g, bf16* l) {
    __builtin_amdgcn_global_load_lds(
        (const __attribute__((address_space(1))) void*)g,
        (__attribute__((address_space(3))) void*)l, 16, 0, 0);
}

#define BAR()   __builtin_amdgcn_s_barrier()
#define LGKM(N) asm volatile("s_waitcnt lgkmcnt(" #N ")" ::: "memory")
#define VMC(N)  asm volatile("s_waitcnt vmcnt(" #N ")" ::: "memory")

// ============================================================================
// Min-sync pipelined GEMM. C = A*B^T + bias. K mult of 64.
// Tile 128(M) x 256(N), BK=64. 512 thr = 8 waves (2Mx4N), wave out 64x64 =
// acc[4][4]. LDS 144KB = 3 bufs x (A 128x64 + B 256x64) -> 1 block/CU.
// Grids fill-exact: GEMM1 768 = 3.0 CU rounds; GEMM2 256 = 1.0 round.
// Swizzle (verified r7/r8, 0 conflicts): read byte ^= (row&7)<<4; inverse on
// GLOBAL source k (kel = ((lane&7)^(lane>>3))*8); linear gload_lds dest.
// ONE barrier / ONE vmcnt / TWO lgkm per K-tile:
//   { issue 16 ds_reads (kk0 8, kk1 8); stage t+2 (6 gloads);
//     lgkmcnt(8) [kk0 ready, kk1 fly]; MFMA kk0;
//     lgkmcnt(0); MFMA kk1; vmcnt(6); BAR }
// vmcnt: 6 issues/tile; at BAR(t) queue=[t+1:6, t+2:6] -> VMC(6) completes
// t+1 before tile t+1 reads it (visible via BAR). Tails (stages guarded
// off): VMC(0). Stage(t+2) overwrites buf (t-1)%3, whose reads all precede
// BAR(t-1) in each wave's program order -> BAR orders write-after-read.
// ============================================================================
template <typename CT>
__global__ __launch_bounds__(512, 2)
void gemm1b(const bf16* __restrict__ A, const bf16* __restrict__ B,
            const float* __restrict__ bias, CT* __restrict__ C,
            int M, int N, int K, int gx) {
    __shared__ alignas(1024) bf16 smem[3][384 * 64];  // per buf: A[0:8192) B[8192:24576)

    const int t    = threadIdx.x;
    const int lane = t & 63;
    const int wid  = t >> 6;
    const int wr   = wid >> 2;   // 0..1  (M half)
    const int wc   = wid & 3;    // 0..3  (N quarter)

    // XCD-aware bijective remap (gridDim.x % 8 == 0)
    const int nwg = gridDim.x;
    const int bid = blockIdx.x;
    const int wg  = (bid & 7) * (nwg >> 3) + (bid >> 3);
    const int m0  = (wg / gx) * 128;
    const int n0  = (wg % gx) * 256;

    const int nt = K / 64;

    // staging coords (inverse swizzle on global k)
    const int srow = lane >> 3;                        // 0..7
    const int kel  = ((lane & 7) ^ (lane >> 3)) * 8;   // pre-swizzled k elems

    auto stageA = [&](int tt) {
        if (tt >= nt) return;
        bf16* lp = &smem[tt % 3][wid * 1024];
        const bf16* gp = A + (size_t)(m0 + wid * 16 + srow) * K + tt * 64 + kel;
        gload_lds16(gp, lp);
        gload_lds16(gp + (size_t)8 * K, lp + 512);
    };
    auto stageB = [&](int tt, int h) {
        if (tt >= nt) return;
        bf16* lp = &smem[tt % 3][8192 + h * 8192 + wid * 1024];
        const bf16* gp = B + (size_t)(n0 + h * 128 + wid * 16 + srow) * K + tt * 64 + kel;
        gload_lds16(gp, lp);
        gload_lds16(gp + (size_t)8 * K, lp + 512);
    };

    // swizzled ds_read of one 16x16x32 fragment (16B aligned)
    const int arow_base = wr * 64 + (lane & 15);
    const int brow_base = wc * 64 + (lane & 15);
    const int kqb       = (lane >> 4) * 16;            // k byte sub-offset
    auto LDA = [&](int buf, int kk, int m) -> bf16x8 {
        const int row = arow_base + m * 16;
        const int ab  = row * 128 + ((kk * 64 + kqb) ^ ((row & 7) << 4));
        return *(const bf16x8*)((const char*)&smem[buf][0] + ab);
    };
    auto LDB = [&](int buf, int kk, int n) -> bf16x8 {
        const int row = brow_base + n * 16;
        const int bb  = 16384 + row * 128 + ((kk * 64 + kqb) ^ ((row & 7) << 4));
        return *(const bf16x8*)((const char*)&smem[buf][0] + bb);
    };

    f32x4 acc[4][4] = {};
    bf16x8 af0[4], bf0[4], af1[4], bf1[4];

    // prologue: stage t0,t1 (12 gloads); VMC(6) => t0 landed
    stageA(0); stageB(0, 0); stageB(0, 1);
    stageA(1); stageB(1, 0); stageB(1, 1);
    VMC(6);
    BAR();

    for (int tt = 0; tt < nt; ++tt) {
        const int buf = tt % 3;

        // issue all 16 frag reads: kk0 first (oldest), then kk1
#pragma unroll
        for (int m = 0; m < 4; ++m) af0[m] = LDA(buf, 0, m);
#pragma unroll
        for (int n = 0; n < 4; ++n) bf0[n] = LDB(buf, 0, n);
#pragma unroll
        for (int m = 0; m < 4; ++m) af1[m] = LDA(buf, 1, m);
#pragma unroll
        for (int n = 0; n < 4; ++n) bf1[n] = LDB(buf, 1, n);
        // stage t+2
        stageA(tt + 2); stageB(tt + 2, 0); stageB(tt + 2, 1);
        // kk0 frags ready (8 oldest); kk1 reads fly under MFMA kk0
        LGKM(8);
        __builtin_amdgcn_s_setprio(1);
#pragma unroll
        for (int m = 0; m < 4; ++m)
#pragma unroll
            for (int n = 0; n < 4; ++n)
                acc[m][n] = __builtin_amdgcn_mfma_f32_16x16x32_bf16(
                    af0[m], bf0[n], acc[m][n], 0, 0, 0);
        __builtin_amdgcn_s_setprio(0);
        LGKM(0);
        __builtin_amdgcn_s_setprio(1);
#pragma unroll
        for (int m = 0; m < 4; ++m)
#pragma unroll
            for (int n = 0; n < 4; ++n)
                acc[m][n] = __builtin_amdgcn_mfma_f32_16x16x32_bf16(
                    af1[m], bf1[n], acc[m][n], 0, 0, 0);
        __builtin_amdgcn_s_setprio(0);
        // t+1 landed (queue [t+1:6, t+2:6]); tails drain fully
        if (tt < nt - 2) { VMC(6); } else { VMC(0); }
        BAR();
    }

    // epilogue
#pragma unroll
    for (int m = 0; m < 4; ++m) {
        const int row = m0 + wr * 64 + m * 16 + (lane >> 4) * 4;
#pragma unroll
        for (int n = 0; n < 4; ++n) {
            const int col = n0 + wc * 64 + n * 16 + (lane & 15);
            const float bval = bias[col];
#pragma unroll
            for (int r = 0; r < 4; ++r)
                store1(&C[(size_t)(row + r) * N + col], acc[m][n][r] + bval);
        }
    }
}

// ---- fused fp32 -> bf16 conversion of TWO buffers, 4 elems/thread ----
__global__ __launch_bounds__(256)
void cvt2_f32_bf16(const float* __restrict__ in1, bf16* __restrict__ out1, int n1,
                   const float* __restrict__ in2, bf16* __restrict__ out2, int n2) {
    int i = blockIdx.x * 256 + threadIdx.x;
    const float* in;
    bf16* out;
    if (i < n1) { in = in1; out = out1; }
    else        { in = in2; out = out2; i -= n1; if (i >= n2) return; }
    float4 v = ((const float4*)in)[i];
    ushort4 o = {f2b(v.x), f2b(v.y), f2b(v.z), f2b(v.w)};
    ((ushort4*)out)[i] = o;
}

// ---- fp32 -> bf16 conversion, 4 elems/thread ----
__global__ __launch_bounds__(256)
void cvt_f32_bf16(const float* __restrict__ in, bf16* __restrict__ out, int n4) {
    int i = blockIdx.x * 256 + threadIdx.x;
    if (i >= n4) return;
    float4 v = ((const float4*)in)[i];
    ushort4 o = {f2b(v.x), f2b(v.y), f2b(v.z), f2b(v.w)};
    ((ushort4*)out)[i] = o;
}

// ---- Per-token attention over heads axis + scrambled T write ----
// stride 68 floats (16B-aligned rows, <=2-way banks), float4 everywhere.
__global__ __launch_bounds__(256)
void attn_kernel(const bf16* __restrict__ qkv, bf16* __restrict__ T) {
    __shared__ float lds[4][48 * 68];

    const int wave = threadIdx.x >> 6;
    const int lane = threadIdx.x & 63;
    const int token = blockIdx.x * 4 + wave;
    const int n = token >> 11;
    const int s = token & 2047;

    float* L = lds[wave];
    const bf16* src = qkv + (size_t)token * 3072;

#pragma unroll
    for (int i = 0; i < 6; ++i) {
        int idx = i * 64 + lane;
        uint4 v = *reinterpret_cast<const uint4*>(src + (size_t)idx * 8);
        int e0 = idx * 8;
        float* dst = &L[(e0 >> 6) * 68 + (e0 & 63)];
        float4 a, b;
        a.x = b2f((unsigned short)(v.x & 0xffff));
        a.y = b2f((unsigned short)(v.x >> 16));
        a.z = b2f((unsigned short)(v.y & 0xffff));
        a.w = b2f((unsigned short)(v.y >> 16));
        b.x = b2f((unsigned short)(v.z & 0xffff));
        b.y = b2f((unsigned short)(v.z >> 16));
        b.z = b2f((unsigned short)(v.w & 0xffff));
        b.w = b2f((unsigned short)(v.w >> 16));
        *(float4*)dst = a;
        *(float4*)(dst + 4) = b;
    }
    __syncthreads();

    const int q0 = lane & 15;
    const int g  = lane >> 4;

    float e[4] = {0.f, 0.f, 0.f, 0.f};
    const float* Qr = &L[q0 * 68];
    const float* K0 = &L[(16 + g * 4) * 68];
#pragma unroll
    for (int d = 0; d < 64; d += 4) {
        float4 q4 = *(const float4*)(Qr + d);
#pragma unroll
        for (int j = 0; j < 4; ++j) {
            float4 k4 = *(const float4*)(K0 + j * 68 + d);
            e[j] += q4.x * k4.x + q4.y * k4.y + q4.z * k4.z + q4.w * k4.w;
        }
    }
#pragma unroll
    for (int j = 0; j < 4; ++j) e[j] *= 0.125f;

    float m = fmaxf(fmaxf(e[0], e[1]), fmaxf(e[2], e[3]));
    m = fmaxf(m, __shfl_xor(m, 16));
    m = fmaxf(m, __shfl_xor(m, 32));
    float p[4], sum = 0.f;
#pragma unroll
    for (int j = 0; j < 4; ++j) { p[j] = __expf(e[j] - m); sum += p[j]; }
    sum += __shfl_xor(sum, 16);
    sum += __shfl_xor(sum, 32);
    const float inv = 1.0f / sum;

    float prow[16];
#pragma unroll
    for (int j = 0; j < 4; ++j) {
        prow[g * 4 + j]         = p[j] * inv;
        prow[((g ^ 1) * 4) + j] = __shfl_xor(p[j], 16) * inv;
        prow[((g ^ 2) * 4) + j] = __shfl_xor(p[j], 32) * inv;
        prow[((g ^ 3) * 4) + j] = __shfl_xor(p[j], 48) * inv;
    }

    const int d0 = g * 16;
    float4 o4[4] = {};
#pragma unroll
    for (int k = 0; k < 16; ++k) {
        const float p1 = prow[k];
        const float* Vr = &L[(32 + k) * 68 + d0];
#pragma unroll
        for (int c = 0; c < 4; ++c) {
            float4 v = *(const float4*)(Vr + c * 4);
            o4[c].x += p1 * v.x; o4[c].y += p1 * v.y;
            o4[c].z += p1 * v.z; o4[c].w += p1 * v.w;
        }
    }
    unsigned short outv[16];
#pragma unroll
    for (int c = 0; c < 4; ++c) {
        outv[c * 4 + 0] = f2b(o4[c].x); outv[c * 4 + 1] = f2b(o4[c].y);
        outv[c * 4 + 2] = f2b(o4[c].z); outv[c * 4 + 3] = f2b(o4[c].w);
    }
    const int sp = q0 * 128 + (s >> 4);
    size_t off = ((size_t)n * 2048 + sp) * 1024 + (size_t)(s & 15) * 64 + d0;
    uint4* dst = reinterpret_cast<uint4*>(T + off);
    const uint4* sv = reinterpret_cast<const uint4*>(outv);
    dst[0] = sv[0];
    dst[1] = sv[1];
}

extern "C" void kernel_launch(void* const* d_in, const int* in_sizes, int n_in,
                              void* d_out, int out_size, void* d_ws, size_t ws_size,
                              hipStream_t stream) {
    const float* x     = (const float*)d_in[0];   // (4,2048,1024)
    const float* w_qkv = (const float*)d_in[1];   // (3072,1024)
    const float* b_qkv = (const float*)d_in[2];   // (3072,)
    const float* w_out = (const float*)d_in[3];   // (1024,1024)
    const float* b_out = (const float*)d_in[4];   // (1024,)
    float* out = (float*)d_out;                   // (4,2048,1024) fp32

    const int M = 8192, E = 3072, K = 1024, D = 1024;

    // ws: [0, 50.33M) qkv bf16 -> later W2b; [50.33M, 67.11M) T bf16.
    // d_out doubles as scratch until GEMM2 rewrites it: W1b then X16.
    bf16* qkv = (bf16*)d_ws;
    bf16* T   = qkv + (size_t)M * E;
    bf16* W2b = qkv;
    bf16* W1b = (bf16*)d_out;
    bf16* X16 = W1b + (size_t)E * K;

    dim3 blk(256);
    const int n1 = M * K / 4, n2 = E * K / 4;

    // 1) x and w_qkv fp32 -> bf16 (one dispatch, d_out scratch)
    cvt2_f32_bf16<<<dim3((n1 + n2) / 256), blk, 0, stream>>>(
        x, X16, n1, w_qkv, W1b, n2);
    // 2) QKV projection: 128x256 tiles, grid 64*12=768 = 3.0 CU rounds
    gemm1b<bf16><<<dim3((M / 128) * (E / 256)), dim3(512), 0, stream>>>(
        X16, W1b, b_qkv, qkv, M, E, K, E / 256);
    // 3) per-token heads-axis attention + scrambled reshape -> bf16 T
    attn_kernel<<<dim3(M / 4), blk, 0, stream>>>(qkv, T);
    // 4) w_out fp32 -> bf16 (dead qkv region)
    cvt_f32_bf16<<<dim3(D * K / 4 / 256), blk, 0, stream>>>(w_out, W2b, D * K / 4);
    // 5) output projection: 128x256 tiles, grid 64*4=256 = 1.0 CU round
    gemm1b<float><<<dim3((M / 128) * (D / 256)), dim3(512), 0, stream>>>(
        T, W2b, b_out, out, M, D, K, D / 256);
}